// Round 11
// baseline (829.779 us; speedup 1.0000x reference)
//
#include <hip/hip_runtime.h>

// MatrixMLP round 11:
//  - Hot kernel: r10 structure but ALL inline-asm lgkmcnt waits replaced by
//    __syncthreads().  The asm "memory" clobber forced per-thread allocas
//    to scratch (348 B/thread -> 178 MB HBM writes, the whole 104us cost);
//    barriers are compiler-understood and don't touch private memory
//    (r5 evidence: same arrays + barriers = 9.4 MB writes).
//  - classify: 32 bucketed worklist counters (one per 128 B line, bucket =
//    blockIdx%32) -> ~6k same-line atomics become ~190/line (r10: 89us of
//    single-line atomic serialization).
//  - repair: block-uniform grid-stride (idx = blk0 + tid) so all threads in
//    a block share trip counts -> barrier-based shared MLP body is legal.

typedef __attribute__((ext_vector_type(8))) short short8;
typedef __attribute__((ext_vector_type(4))) float f32x4;

__device__ __forceinline__ short f2bf(float f) {
  unsigned int u = __float_as_uint(f);
  u += 0x7fffu + ((u >> 16) & 1u);
  return (short)(u >> 16);
}

#define GUARD_THETA 1.0e-4f
#define WFRAG_BYTES 26624        // 26 frags * 64 lanes * 16 B
#define WL_CNT_OFF  26624        // 32 counters, stride 32 ints (128 B) = 4 KB
#define WL_LIST_OFF 30720
#define NBUCK 32
#define RBLK 128                 // repair grid

// ---- per-wave LDS chunk (bytes); strides odd multiples of 16B ----
#define W_A    0        // 64 rows * 80 B
#define W_H1   5120     // 16 rows * 272 B
#define W_H2   9472     // 16 rows * 144 B
#define W_D    11776    // 64 rows * 20 B
#define W_SZ   13056
#define SMEM_SZ (4 * W_SZ)   // 52224 B -> 3 blocks/CU (LDS-limited)

// ---------------- weight fragment pre-pack (+ counter reset) ----------------
__global__ void pack_w(const float* __restrict__ W1, const float* __restrict__ W2,
                       const float* __restrict__ W3, short* __restrict__ ws,
                       int* __restrict__ wl_cnt)
{
  if (wl_cnt && blockIdx.x == 0 && threadIdx.x < NBUCK)
    wl_cnt[threadIdx.x * 32] = 0;
  int t = blockIdx.x * 256 + threadIdx.x;
  if (t >= 26 * 64) return;
  int fid = t >> 6, lane = t & 63, l15 = lane & 15, lg = lane >> 4;
  short8 v;
  if (fid < 8) {
    int col = fid * 16 + l15;
    #pragma unroll
    for (int j = 0; j < 8; ++j) {
      int k = lg * 8 + j;
      v[j] = (k < 24) ? f2bf(W1[k * 128 + col]) : (short)0;
    }
  } else if (fid < 24) {
    int q = fid - 8, kt = q >> 2, nt = q & 3, col = nt * 16 + l15;
    #pragma unroll
    for (int j = 0; j < 8; ++j)
      v[j] = f2bf(W2[(kt * 32 + lg * 8 + j) * 64 + col]);
  } else {
    int kt = fid - 24;
    #pragma unroll
    for (int j = 0; j < 8; ++j)
      v[j] = (l15 < 4) ? f2bf(W3[(kt * 32 + lg * 8 + j) * 4 + l15]) : (short)0;
  }
  ((short8*)ws)[t] = v;
}

// ---------------- classify: bucketed repair worklist ----------------
__global__ __launch_bounds__(256) void classify(
    const float* __restrict__ x, int Bn,
    int* __restrict__ wl_cnt, int* __restrict__ wl_list,
    int nbuck, int cap)
{
  const int lane = threadIdx.x & 63;
  const long long g = (long long)blockIdx.x * 256 + threadIdx.x;
  bool unsafe_row = false;
  if (g < Bn) {
    const float* xr = x + g * 20;
    float xf[16];
    #pragma unroll
    for (int i = 0; i < 4; ++i) {
      f32x4 v = *(const f32x4*)(xr + i * 4);
      xf[i*4+0] = v[0]; xf[i*4+1] = v[1]; xf[i*4+2] = v[2]; xf[i*4+3] = v[3];
    }
    float a00 = xf[0], a01 = xf[4], a02 = xf[8],  a03 = xf[12];
    float a10 = xf[1], a11 = xf[5], a12 = xf[9],  a13 = xf[13];
    float a20 = xf[2], a21 = xf[6], a22 = xf[10], a23 = xf[14];
    float a30 = xf[3], a31 = xf[7], a32 = xf[11], a33 = xf[15];
    float s0 = a00*a11 - a10*a01, s1 = a00*a12 - a10*a02, s2 = a00*a13 - a10*a03;
    float s3 = a01*a12 - a11*a02, s4 = a01*a13 - a11*a03, s5 = a02*a13 - a12*a03;
    float c0 = a20*a31 - a30*a21, c1 = a20*a32 - a30*a22, c2 = a20*a33 - a30*a23;
    float c3 = a21*a32 - a31*a22, c4 = a21*a33 - a31*a23, c5 = a22*a33 - a32*a23;
    float det = s0*c5 - s1*c4 + s2*c3 + s3*c2 - s4*c1 + s5*c0;
    float T = a00*a00 + a01*a01 + a02*a02 + a03*a03
            + a10*a10 + a11*a11 + a12*a12 + a13*a13
            + a20*a20 + a21*a21 + a22*a22 + a23*a23
            + a30*a30 + a31*a31 + a32*a32 + a33*a33;
    // 1.004x looser bar than hot => superset of hot-unsafe rows
    unsafe_row = !(__builtin_fabsf(det) > GUARD_THETA * 1.004f * T * T);
  }
  unsigned long long m = __ballot(unsafe_row);
  if (m) {
    const int bucket = blockIdx.x % nbuck;
    int leader = (int)__builtin_ctzll(m);
    int base = 0;
    if (lane == leader)
      base = atomicAdd(&wl_cnt[bucket * 32], (int)__builtin_popcountll(m));
    base = __shfl(base, leader, 64);
    if (unsafe_row) {
      int lt = (int)__builtin_popcountll(m & ((1ull << lane) - 1ull));
      wl_list[(size_t)bucket * cap + base + lt] = (int)g;
    }
  }
}

// ---------------- shared MFMA MLP body (barrier-synced, all 256 threads) ----
// Caller wrote all A-rows of its wave's LDS chunk; reads delta from W_D after.
__device__ __forceinline__ void mlp_wave(
    unsigned char* wsm, int lane, int l15, int lg,
    const short* __restrict__ wfrag,
    const float* __restrict__ W1, const float* __restrict__ b1,
    const float* __restrict__ W2, const float* __restrict__ b2,
    const float* __restrict__ W3, const float* __restrict__ b3)
{
  const f32x4 fzero = {0.0f, 0.0f, 0.0f, 0.0f};
  const short8* wv4 = (const short8*)wfrag;

  short8 bf1[8];
  if (wfrag) {
    #pragma unroll
    for (int nt = 0; nt < 8; ++nt) bf1[nt] = wv4[nt * 64 + lane];
  } else {
    #pragma unroll
    for (int nt = 0; nt < 8; ++nt) {
      int col = nt * 16 + l15;
      #pragma unroll
      for (int j = 0; j < 8; ++j) {
        int k = lg * 8 + j;
        bf1[nt][j] = (k < 24) ? f2bf(W1[k * 128 + col]) : (short)0;
      }
    }
  }
  float bias1[8], bias2[4], bias3;
  #pragma unroll
  for (int nt = 0; nt < 8; ++nt) bias1[nt] = b1[nt * 16 + l15];
  #pragma unroll
  for (int nt = 0; nt < 4; ++nt) bias2[nt] = b2[nt * 16 + l15];
  bias3 = b3[l15 & 3];

  __syncthreads();   // A-rows (and previous-iteration state) visible

  for (int t = 0; t < 4; ++t) {
    // layer 1: (16x32)@(32x128) + b1, ReLU -> H1 tile
    {
      short8 a = *(const short8*)(wsm + W_A + (t * 16 + l15) * 80 + lg * 16);
      f32x4 acc[8];
      #pragma unroll
      for (int nt = 0; nt < 8; ++nt)
        acc[nt] = __builtin_amdgcn_mfma_f32_16x16x32_bf16(a, bf1[nt], fzero, 0, 0, 0);
      #pragma unroll
      for (int nt = 0; nt < 8; ++nt) {
        #pragma unroll
        for (int j = 0; j < 4; ++j) {
          float h = acc[nt][j] + bias1[nt];
          h = h > 0.0f ? h : 0.0f;
          *(short*)(wsm + W_H1 + (lg * 4 + j) * 272 + (nt * 16 + l15) * 2) = f2bf(h);
        }
      }
    }
    __syncthreads();   // H1 visible; also orders H2 WAR (L3(t-1) read done)

    // layer 2: (16x128)@(128x64) + b2, ReLU -> H2 tile
    {
      f32x4 acc2[4] = {fzero, fzero, fzero, fzero};
      #pragma unroll
      for (int kt = 0; kt < 4; ++kt) {
        short8 a2 = *(const short8*)(wsm + W_H1 + l15 * 272 + kt * 64 + lg * 16);
        #pragma unroll
        for (int nt = 0; nt < 4; ++nt) {
          short8 bw;
          if (wfrag) bw = wv4[(8 + kt * 4 + nt) * 64 + lane];
          else {
            int col = nt * 16 + l15;
            #pragma unroll
            for (int j = 0; j < 8; ++j)
              bw[j] = f2bf(W2[(kt * 32 + lg * 8 + j) * 64 + col]);
          }
          acc2[nt] = __builtin_amdgcn_mfma_f32_16x16x32_bf16(a2, bw, acc2[nt], 0, 0, 0);
        }
      }
      #pragma unroll
      for (int nt = 0; nt < 4; ++nt) {
        #pragma unroll
        for (int j = 0; j < 4; ++j) {
          float h = acc2[nt][j] + bias2[nt];
          h = h > 0.0f ? h : 0.0f;
          *(short*)(wsm + W_H2 + (lg * 4 + j) * 144 + (nt * 16 + l15) * 2) = f2bf(h);
        }
      }
    }
    __syncthreads();   // H2 visible; also orders H1 WAR (L2 reads done)

    // layer 3: (16x64)@(64x16[4]) + b3 -> delta
    {
      f32x4 acc3 = fzero;
      #pragma unroll
      for (int kt = 0; kt < 2; ++kt) {
        short8 a3 = *(const short8*)(wsm + W_H2 + l15 * 144 + kt * 64 + lg * 16);
        short8 bw;
        if (wfrag) bw = wv4[(24 + kt) * 64 + lane];
        else {
          #pragma unroll
          for (int j = 0; j < 8; ++j)
            bw[j] = (l15 < 4) ? f2bf(W3[(kt * 32 + lg * 8 + j) * 4 + l15]) : (short)0;
        }
        acc3 = __builtin_amdgcn_mfma_f32_16x16x32_bf16(a3, bw, acc3, 0, 0, 0);
      }
      if (l15 < 4) {
        #pragma unroll
        for (int j = 0; j < 4; ++j)
          *(float*)(wsm + W_D + (t * 16 + lg * 4 + j) * 20 + l15 * 4) = acc3[j] + bias3;
      }
    }
  }
  __syncthreads();   // delta visible
}

// ---------------- hot kernel ----------------
__global__ __launch_bounds__(256, 2) void MatrixMLP_54047868453544_kernel(
    const float* __restrict__ x,
    const float* __restrict__ W1, const float* __restrict__ b1,
    const float* __restrict__ W2, const float* __restrict__ b2,
    const float* __restrict__ W3, const float* __restrict__ b3,
    const short* __restrict__ wfrag,
    float* __restrict__ out, int Bn)
{
  __shared__ __align__(16) unsigned char smem[SMEM_SZ];
  const int tid  = threadIdx.x;
  const int lane = tid & 63;
  const int wv   = tid >> 6;
  const int l15  = lane & 15;
  const int lg   = lane >> 4;
  unsigned char* wsm = smem + wv * W_SZ;
  const long long g = (long long)blockIdx.x * 256 + wv * 64 + lane;

  // ---- load row (1 row/lane) ----
  float xf[20];
  if (g < Bn) {
    const float* xr = x + g * 20;
    #pragma unroll
    for (int i = 0; i < 5; ++i) {
      f32x4 v = *(const f32x4*)(xr + i * 4);
      xf[i*4+0] = v[0]; xf[i*4+1] = v[1]; xf[i*4+2] = v[2]; xf[i*4+3] = v[3];
    }
  } else {
    #pragma unroll
    for (int i = 0; i < 20; ++i) xf[i] = 0.0f;
  }

  // ---- f32 Cramer solve with safety guard (H[i][j] = x[j*4+i]) ----
  float xls[4];
  {
    float a00 = xf[0], a01 = xf[4], a02 = xf[8],  a03 = xf[12];
    float a10 = xf[1], a11 = xf[5], a12 = xf[9],  a13 = xf[13];
    float a20 = xf[2], a21 = xf[6], a22 = xf[10], a23 = xf[14];
    float a30 = xf[3], a31 = xf[7], a32 = xf[11], a33 = xf[15];
    float y0 = xf[16], y1 = xf[17], y2 = xf[18], y3 = xf[19];

    float s0 = a00*a11 - a10*a01, s1 = a00*a12 - a10*a02, s2 = a00*a13 - a10*a03;
    float s3 = a01*a12 - a11*a02, s4 = a01*a13 - a11*a03, s5 = a02*a13 - a12*a03;
    float c0 = a20*a31 - a30*a21, c1 = a20*a32 - a30*a22, c2 = a20*a33 - a30*a23;
    float c3 = a21*a32 - a31*a22, c4 = a21*a33 - a31*a23, c5 = a22*a33 - a32*a23;
    float det = s0*c5 - s1*c4 + s2*c3 + s3*c2 - s4*c1 + s5*c0;

    float T = a00*a00 + a01*a01 + a02*a02 + a03*a03
            + a10*a10 + a11*a11 + a12*a12 + a13*a13
            + a20*a20 + a21*a21 + a22*a22 + a23*a23
            + a30*a30 + a31*a31 + a32*a32 + a33*a33;

    float xd0 = 0.0f, xd1 = 0.0f, xd2 = 0.0f, xd3 = 0.0f;
    if (__builtin_fabsf(det) > GUARD_THETA * T * T) {
      float rdet = 1.0f / det;
      {
        float q0 =   a11*c5 - a12*c4 + a13*c3;
        float q1 = -(a01*c5 - a02*c4 + a03*c3);
        float q2 =   a31*s5 - a32*s4 + a33*s3;
        float q3 = -(a21*s5 - a22*s4 + a23*s3);
        xd0 = rdet * (q0*y0 + q1*y1 + q2*y2 + q3*y3);
      }
      {
        float q0 = -(a10*c5 - a12*c2 + a13*c1);
        float q1 =   a00*c5 - a02*c2 + a03*c1;
        float q2 = -(a30*s5 - a32*s2 + a33*s1);
        float q3 =   a20*s5 - a22*s2 + a23*s1;
        xd1 = rdet * (q0*y0 + q1*y1 + q2*y2 + q3*y3);
      }
      {
        float q0 =   a10*c4 - a11*c2 + a13*c0;
        float q1 = -(a00*c4 - a01*c2 + a03*c0);
        float q2 =   a30*s4 - a31*s2 + a33*s0;
        float q3 = -(a20*s4 - a21*s2 + a23*s0);
        xd2 = rdet * (q0*y0 + q1*y1 + q2*y2 + q3*y3);
      }
      {
        float q0 = -(a10*c3 - a11*c1 + a12*c0);
        float q1 =   a00*c3 - a01*c1 + a02*c0;
        float q2 = -(a30*s3 - a31*s1 + a32*s0);
        float q3 =   a20*s3 - a21*s1 + a22*s0;
        xd3 = rdet * (q0*y0 + q1*y1 + q2*y2 + q3*y3);
      }
    }
    // unsafe lanes keep xd=0: placeholder, overwritten by repair kernel

    float xdv[4] = {xd0, xd1, xd2, xd3};
    short rowbuf[32];
    #pragma unroll
    for (int i = 0; i < 20; ++i) rowbuf[i] = f2bf(xf[i]);
    #pragma unroll
    for (int i = 0; i < 4; ++i) {
      float v = xdv[i];
      if (v != v) v = 0.0f;
      v = fminf(fmaxf(v, 0.0f), 1.0f);
      xls[i] = v;
      rowbuf[20 + i] = f2bf(v);
    }
    #pragma unroll
    for (int i = 24; i < 32; ++i) rowbuf[i] = 0;
    short8* dst = (short8*)(wsm + W_A + lane * 80);
    #pragma unroll
    for (int i = 0; i < 4; ++i) dst[i] = *(short8*)(rowbuf + i * 8);
  }

  // ---- MFMA MLP (barrier-synced shared body) ----
  mlp_wave(wsm, lane, l15, lg, wfrag, W1, b1, W2, b2, W3, b3);

  // ---- epilogue: out = clip(x_ls + delta, 0, 1) ----
  if (g < Bn) {
    const unsigned char* dl = wsm + W_D + lane * 20;
    f32x4 o;
    #pragma unroll
    for (int c = 0; c < 4; ++c) {
      float v = xls[c] + *(const float*)(dl + c * 4);
      o[c] = fminf(fmaxf(v, 0.0f), 1.0f);
    }
    *(f32x4*)(out + g * 4) = o;
  }
}

// ---------------- repair kernel (block-uniform stride; barrier-safe) --------
__global__ __launch_bounds__(256) void repair_rows(
    const float* __restrict__ x,
    const float* __restrict__ W1, const float* __restrict__ b1,
    const float* __restrict__ W2, const float* __restrict__ b2,
    const float* __restrict__ W3, const float* __restrict__ b3,
    const short* __restrict__ wfrag,
    float* __restrict__ out, int Bn,
    const int* __restrict__ wl_cnt, const int* __restrict__ wl_list,
    int use_wl, int nbuck, int cap)
{
  __shared__ __align__(16) unsigned char smem[SMEM_SZ];
  const int tid  = threadIdx.x;
  const int lane = tid & 63;
  const int wv   = tid >> 6;
  const int l15  = lane & 15;
  const int lg   = lane >> 4;
  unsigned char* wsm = smem + wv * W_SZ;

  for (int b = 0; b < (use_wl ? nbuck : 1); ++b) {
    const int cnt = use_wl ? wl_cnt[b * 32] : Bn;
    const int* lst = wl_list + (size_t)b * cap;

    // blk0 identical across the block -> uniform trip count -> barriers safe
    for (long long blk0 = (long long)blockIdx.x * 256; blk0 < cnt;
         blk0 += (long long)gridDim.x * 256) {
      const long long idx = blk0 + tid;
      int g = -1;
      if (idx < cnt) g = use_wl ? lst[idx] : (int)idx;

      float xf[20];
      if (g >= 0) {
        const float* xr = x + (long long)g * 20;
        #pragma unroll
        for (int i = 0; i < 5; ++i) {
          f32x4 v = *(const f32x4*)(xr + i * 4);
          xf[i*4+0] = v[0]; xf[i*4+1] = v[1]; xf[i*4+2] = v[2]; xf[i*4+3] = v[3];
        }
      } else {
        #pragma unroll
        for (int i = 0; i < 20; ++i) xf[i] = 0.0f;
      }

      if (!use_wl && g >= 0) {
        // fallback scan: keep only rows failing the hot guard
        float a00 = xf[0], a01 = xf[4], a02 = xf[8],  a03 = xf[12];
        float a10 = xf[1], a11 = xf[5], a12 = xf[9],  a13 = xf[13];
        float a20 = xf[2], a21 = xf[6], a22 = xf[10], a23 = xf[14];
        float a30 = xf[3], a31 = xf[7], a32 = xf[11], a33 = xf[15];
        float s0 = a00*a11 - a10*a01, s1 = a00*a12 - a10*a02, s2 = a00*a13 - a10*a03;
        float s3 = a01*a12 - a11*a02, s4 = a01*a13 - a11*a03, s5 = a02*a13 - a12*a03;
        float c0 = a20*a31 - a30*a21, c1 = a20*a32 - a30*a22, c2 = a20*a33 - a30*a23;
        float c3 = a21*a32 - a31*a22, c4 = a21*a33 - a31*a23, c5 = a22*a33 - a32*a23;
        float det = s0*c5 - s1*c4 + s2*c3 + s3*c2 - s4*c1 + s5*c0;
        float T = a00*a00 + a01*a01 + a02*a02 + a03*a03
                + a10*a10 + a11*a11 + a12*a12 + a13*a13
                + a20*a20 + a21*a21 + a22*a22 + a23*a23
                + a30*a30 + a31*a31 + a32*a32 + a33*a33;
        if (__builtin_fabsf(det) > GUARD_THETA * T * T) g = -1;
      }

      // ---- f64 Jacobi eigensolve of G = H^T H + jax rcond truncation ----
      // (zero input rows -> all-zero G -> xd stays 0; no NaNs)
      double G[4][4], V[4][4], rhs[4];
      #pragma unroll
      for (int p = 0; p < 4; ++p) {
        #pragma unroll
        for (int q = 0; q < 4; ++q) {
          double s = 0.0;
          #pragma unroll
          for (int k = 0; k < 4; ++k)
            s += (double)xf[p * 4 + k] * (double)xf[q * 4 + k];
          G[p][q] = s;
          V[p][q] = (p == q) ? 1.0 : 0.0;
        }
        double s = 0.0;
        #pragma unroll
        for (int k = 0; k < 4; ++k) s += (double)xf[p * 4 + k] * (double)xf[16 + k];
        rhs[p] = s;
      }
      #pragma unroll
      for (int sweep = 0; sweep < 6; ++sweep) {
        #pragma unroll
        for (int pq = 0; pq < 6; ++pq) {
          constexpr int PP[6] = {0, 0, 0, 1, 1, 2};
          constexpr int QQ[6] = {1, 2, 3, 2, 3, 3};
          const int p = PP[pq], q = QQ[pq];
          double apq = G[p][q];
          double c, s;
          if (apq != 0.0) {
            double tau = (G[q][q] - G[p][p]) / (2.0 * apq);
            double t = (tau >= 0.0 ? 1.0 : -1.0) / (fabs(tau) + sqrt(1.0 + tau * tau));
            c = 1.0 / sqrt(1.0 + t * t);
            s = t * c;
          } else { c = 1.0; s = 0.0; }
          #pragma unroll
          for (int k = 0; k < 4; ++k) {
            double gpk = G[p][k], gqk = G[q][k];
            G[p][k] = c * gpk - s * gqk;
            G[q][k] = s * gpk + c * gqk;
          }
          #pragma unroll
          for (int k = 0; k < 4; ++k) {
            double gkp = G[k][p], gkq = G[k][q];
            G[k][p] = c * gkp - s * gkq;
            G[k][q] = s * gkp + c * gkq;
          }
          #pragma unroll
          for (int k = 0; k < 4; ++k) {
            double vkp = V[k][p], vkq = V[k][q];
            V[k][p] = c * vkp - s * vkq;
            V[k][q] = s * vkp + c * vkq;
          }
        }
      }
      double lam[4] = {G[0][0], G[1][1], G[2][2], G[3][3]};
      double lmax = fmax(fmax(lam[0], lam[1]), fmax(lam[2], lam[3]));
      lmax = fmax(lmax, 0.0);
      const double cut = 2.27373675443232e-11 * lmax;  // (4.7683716e-6)^2
      double xd0 = 0.0, xd1 = 0.0, xd2 = 0.0, xd3 = 0.0;
      #pragma unroll
      for (int k = 0; k < 4; ++k) {
        if (lam[k] > cut && lam[k] > 0.0) {
          double coef = (V[0][k] * rhs[0] + V[1][k] * rhs[1] +
                         V[2][k] * rhs[2] + V[3][k] * rhs[3]) / lam[k];
          xd0 += V[0][k] * coef;
          xd1 += V[1][k] * coef;
          xd2 += V[2][k] * coef;
          xd3 += V[3][k] * coef;
        }
      }

      float xls[4];
      {
        double xd[4] = {xd0, xd1, xd2, xd3};
        short rowbuf[32];
        #pragma unroll
        for (int i = 0; i < 20; ++i) rowbuf[i] = f2bf(xf[i]);
        #pragma unroll
        for (int i = 0; i < 4; ++i) {
          float v = (float)xd[i];
          if (v != v) v = 0.0f;
          v = fminf(fmaxf(v, 0.0f), 1.0f);
          xls[i] = v;
          rowbuf[20 + i] = f2bf(v);
        }
        #pragma unroll
        for (int i = 24; i < 32; ++i) rowbuf[i] = 0;
        short8* dst = (short8*)(wsm + W_A + lane * 80);
        #pragma unroll
        for (int i = 0; i < 4; ++i) dst[i] = *(short8*)(rowbuf + i * 8);
      }

      mlp_wave(wsm, lane, l15, lg, wfrag, W1, b1, W2, b2, W3, b3);

      if (g >= 0) {
        const unsigned char* dl = wsm + W_D + lane * 20;
        f32x4 o;
        #pragma unroll
        for (int c = 0; c < 4; ++c) {
          float v = xls[c] + *(const float*)(dl + c * 4);
          o[c] = fminf(fmaxf(v, 0.0f), 1.0f);
        }
        *(f32x4*)(out + (long long)g * 4) = o;
      }
    }
  }
}

extern "C" void kernel_launch(void* const* d_in, const int* in_sizes, int n_in,
                              void* d_out, int out_size, void* d_ws, size_t ws_size,
                              hipStream_t stream) {
  (void)n_in;
  const float* x  = (const float*)d_in[0];
  const float* W1 = (const float*)d_in[1];
  const float* b1 = (const float*)d_in[2];
  const float* W2 = (const float*)d_in[3];
  const float* b2 = (const float*)d_in[4];
  const float* W3 = (const float*)d_in[5];
  const float* b3 = (const float*)d_in[6];
  float* out = (float*)d_out;
  const int Bn = in_sizes[0] / 20;
  const int nblk = (Bn + 255) / 256;

  short* wfrag = nullptr;
  int* wl_cnt = nullptr;
  int* wl_list = nullptr;
  int use_wl = 0, nbuck = 1, cap = 0;
  if (ws_size >= (size_t)WFRAG_BYTES) wfrag = (short*)d_ws;
  {
    // try 32 buckets, then 1 bucket, else full-scan fallback
    int cap32 = 256 * ((nblk + NBUCK - 1) / NBUCK);
    int cap1  = 256 * nblk;
    if (ws_size >= (size_t)WL_LIST_OFF + 4ull * NBUCK * (size_t)cap32) {
      nbuck = NBUCK; cap = cap32; use_wl = 1;
    } else if (ws_size >= (size_t)WL_LIST_OFF + 4ull * (size_t)cap1) {
      nbuck = 1; cap = cap1; use_wl = 1;
    }
    if (use_wl) {
      wl_cnt  = (int*)((char*)d_ws + WL_CNT_OFF);
      wl_list = (int*)((char*)d_ws + WL_LIST_OFF);
    }
  }

  (void)hipGetLastError();
  if (wfrag) pack_w<<<7, 256, 0, stream>>>(W1, W2, W3, wfrag, wl_cnt);

  if (use_wl)
    classify<<<nblk, 256, 0, stream>>>(x, Bn, wl_cnt, wl_list, nbuck, cap);

  MatrixMLP_54047868453544_kernel<<<nblk, 256, 0, stream>>>(
      x, W1, b1, W2, b2, W3, b3, wfrag, out, Bn);

  repair_rows<<<RBLK, 256, 0, stream>>>(x, W1, b1, W2, b2, W3, b3, wfrag,
                                        out, Bn, wl_cnt, wl_list,
                                        use_wl, nbuck, cap);
  hipError_t e = hipGetLastError();
  if (e != hipSuccess) {
    int byte = 0x40 + ((int)e & 63);
    hipMemsetAsync(d_out, byte, (size_t)out_size * sizeof(float), stream);
  }
}

// Round 12
// 121.222 us; speedup vs baseline: 6.8451x; 6.8451x over previous
//
#include <hip/hip_runtime.h>

// MatrixMLP round 12:
//  - repair_rows: buckets processed IN PARALLEL (bucket = blockIdx % 32,
//    sub-stride within bucket) instead of r11's serial 32-bucket loop that
//    left 125/128 blocks idle (740us).  Jacobi sweep loop rolled
//    (#pragma unroll 1) to cut the 256-VGPR / code-bloat cost.
//  - hot kernel / classify / pack: byte-identical to round 11 (hot is now
//    spill-free after the asm->__syncthreads fix; classify bucketed).

typedef __attribute__((ext_vector_type(8))) short short8;
typedef __attribute__((ext_vector_type(4))) float f32x4;

__device__ __forceinline__ short f2bf(float f) {
  unsigned int u = __float_as_uint(f);
  u += 0x7fffu + ((u >> 16) & 1u);
  return (short)(u >> 16);
}

#define GUARD_THETA 1.0e-4f
#define WFRAG_BYTES 26624        // 26 frags * 64 lanes * 16 B
#define WL_CNT_OFF  26624        // 32 counters, stride 32 ints (128 B) = 4 KB
#define WL_LIST_OFF 30720
#define NBUCK 32
#define RBLK 256                 // repair grid: 8 blocks per bucket

// ---- per-wave LDS chunk (bytes); strides odd multiples of 16B ----
#define W_A    0        // 64 rows * 80 B
#define W_H1   5120     // 16 rows * 272 B
#define W_H2   9472     // 16 rows * 144 B
#define W_D    11776    // 64 rows * 20 B
#define W_SZ   13056
#define SMEM_SZ (4 * W_SZ)   // 52224 B -> 3 blocks/CU (LDS-limited)

// ---------------- weight fragment pre-pack (+ counter reset) ----------------
__global__ void pack_w(const float* __restrict__ W1, const float* __restrict__ W2,
                       const float* __restrict__ W3, short* __restrict__ ws,
                       int* __restrict__ wl_cnt)
{
  if (wl_cnt && blockIdx.x == 0 && threadIdx.x < NBUCK)
    wl_cnt[threadIdx.x * 32] = 0;
  int t = blockIdx.x * 256 + threadIdx.x;
  if (t >= 26 * 64) return;
  int fid = t >> 6, lane = t & 63, l15 = lane & 15, lg = lane >> 4;
  short8 v;
  if (fid < 8) {
    int col = fid * 16 + l15;
    #pragma unroll
    for (int j = 0; j < 8; ++j) {
      int k = lg * 8 + j;
      v[j] = (k < 24) ? f2bf(W1[k * 128 + col]) : (short)0;
    }
  } else if (fid < 24) {
    int q = fid - 8, kt = q >> 2, nt = q & 3, col = nt * 16 + l15;
    #pragma unroll
    for (int j = 0; j < 8; ++j)
      v[j] = f2bf(W2[(kt * 32 + lg * 8 + j) * 64 + col]);
  } else {
    int kt = fid - 24;
    #pragma unroll
    for (int j = 0; j < 8; ++j)
      v[j] = (l15 < 4) ? f2bf(W3[(kt * 32 + lg * 8 + j) * 4 + l15]) : (short)0;
  }
  ((short8*)ws)[t] = v;
}

// ---------------- classify: bucketed repair worklist ----------------
__global__ __launch_bounds__(256) void classify(
    const float* __restrict__ x, int Bn,
    int* __restrict__ wl_cnt, int* __restrict__ wl_list,
    int nbuck, int cap)
{
  const int lane = threadIdx.x & 63;
  const long long g = (long long)blockIdx.x * 256 + threadIdx.x;
  bool unsafe_row = false;
  if (g < Bn) {
    const float* xr = x + g * 20;
    float xf[16];
    #pragma unroll
    for (int i = 0; i < 4; ++i) {
      f32x4 v = *(const f32x4*)(xr + i * 4);
      xf[i*4+0] = v[0]; xf[i*4+1] = v[1]; xf[i*4+2] = v[2]; xf[i*4+3] = v[3];
    }
    float a00 = xf[0], a01 = xf[4], a02 = xf[8],  a03 = xf[12];
    float a10 = xf[1], a11 = xf[5], a12 = xf[9],  a13 = xf[13];
    float a20 = xf[2], a21 = xf[6], a22 = xf[10], a23 = xf[14];
    float a30 = xf[3], a31 = xf[7], a32 = xf[11], a33 = xf[15];
    float s0 = a00*a11 - a10*a01, s1 = a00*a12 - a10*a02, s2 = a00*a13 - a10*a03;
    float s3 = a01*a12 - a11*a02, s4 = a01*a13 - a11*a03, s5 = a02*a13 - a12*a03;
    float c0 = a20*a31 - a30*a21, c1 = a20*a32 - a30*a22, c2 = a20*a33 - a30*a23;
    float c3 = a21*a32 - a31*a22, c4 = a21*a33 - a31*a23, c5 = a22*a33 - a32*a23;
    float det = s0*c5 - s1*c4 + s2*c3 + s3*c2 - s4*c1 + s5*c0;
    float T = a00*a00 + a01*a01 + a02*a02 + a03*a03
            + a10*a10 + a11*a11 + a12*a12 + a13*a13
            + a20*a20 + a21*a21 + a22*a22 + a23*a23
            + a30*a30 + a31*a31 + a32*a32 + a33*a33;
    // 1.004x looser bar than hot => superset of hot-unsafe rows
    unsafe_row = !(__builtin_fabsf(det) > GUARD_THETA * 1.004f * T * T);
  }
  unsigned long long m = __ballot(unsafe_row);
  if (m) {
    const int bucket = blockIdx.x % nbuck;
    int leader = (int)__builtin_ctzll(m);
    int base = 0;
    if (lane == leader)
      base = atomicAdd(&wl_cnt[bucket * 32], (int)__builtin_popcountll(m));
    base = __shfl(base, leader, 64);
    if (unsafe_row) {
      int lt = (int)__builtin_popcountll(m & ((1ull << lane) - 1ull));
      wl_list[(size_t)bucket * cap + base + lt] = (int)g;
    }
  }
}

// ---------------- shared MFMA MLP body (barrier-synced, all 256 threads) ----
__device__ __forceinline__ void mlp_wave(
    unsigned char* wsm, int lane, int l15, int lg,
    const short* __restrict__ wfrag,
    const float* __restrict__ W1, const float* __restrict__ b1,
    const float* __restrict__ W2, const float* __restrict__ b2,
    const float* __restrict__ W3, const float* __restrict__ b3)
{
  const f32x4 fzero = {0.0f, 0.0f, 0.0f, 0.0f};
  const short8* wv4 = (const short8*)wfrag;

  short8 bf1[8];
  if (wfrag) {
    #pragma unroll
    for (int nt = 0; nt < 8; ++nt) bf1[nt] = wv4[nt * 64 + lane];
  } else {
    #pragma unroll
    for (int nt = 0; nt < 8; ++nt) {
      int col = nt * 16 + l15;
      #pragma unroll
      for (int j = 0; j < 8; ++j) {
        int k = lg * 8 + j;
        bf1[nt][j] = (k < 24) ? f2bf(W1[k * 128 + col]) : (short)0;
      }
    }
  }
  float bias1[8], bias2[4], bias3;
  #pragma unroll
  for (int nt = 0; nt < 8; ++nt) bias1[nt] = b1[nt * 16 + l15];
  #pragma unroll
  for (int nt = 0; nt < 4; ++nt) bias2[nt] = b2[nt * 16 + l15];
  bias3 = b3[l15 & 3];

  __syncthreads();   // A-rows (and previous-iteration state) visible

  for (int t = 0; t < 4; ++t) {
    // layer 1: (16x32)@(32x128) + b1, ReLU -> H1 tile
    {
      short8 a = *(const short8*)(wsm + W_A + (t * 16 + l15) * 80 + lg * 16);
      f32x4 acc[8];
      #pragma unroll
      for (int nt = 0; nt < 8; ++nt)
        acc[nt] = __builtin_amdgcn_mfma_f32_16x16x32_bf16(a, bf1[nt], fzero, 0, 0, 0);
      #pragma unroll
      for (int nt = 0; nt < 8; ++nt) {
        #pragma unroll
        for (int j = 0; j < 4; ++j) {
          float h = acc[nt][j] + bias1[nt];
          h = h > 0.0f ? h : 0.0f;
          *(short*)(wsm + W_H1 + (lg * 4 + j) * 272 + (nt * 16 + l15) * 2) = f2bf(h);
        }
      }
    }
    __syncthreads();   // H1 visible

    // layer 2: (16x128)@(128x64) + b2, ReLU -> H2 tile
    {
      f32x4 acc2[4] = {fzero, fzero, fzero, fzero};
      #pragma unroll
      for (int kt = 0; kt < 4; ++kt) {
        short8 a2 = *(const short8*)(wsm + W_H1 + l15 * 272 + kt * 64 + lg * 16);
        #pragma unroll
        for (int nt = 0; nt < 4; ++nt) {
          short8 bw;
          if (wfrag) bw = wv4[(8 + kt * 4 + nt) * 64 + lane];
          else {
            int col = nt * 16 + l15;
            #pragma unroll
            for (int j = 0; j < 8; ++j)
              bw[j] = f2bf(W2[(kt * 32 + lg * 8 + j) * 64 + col]);
          }
          acc2[nt] = __builtin_amdgcn_mfma_f32_16x16x32_bf16(a2, bw, acc2[nt], 0, 0, 0);
        }
      }
      #pragma unroll
      for (int nt = 0; nt < 4; ++nt) {
        #pragma unroll
        for (int j = 0; j < 4; ++j) {
          float h = acc2[nt][j] + bias2[nt];
          h = h > 0.0f ? h : 0.0f;
          *(short*)(wsm + W_H2 + (lg * 4 + j) * 144 + (nt * 16 + l15) * 2) = f2bf(h);
        }
      }
    }
    __syncthreads();   // H2 visible; orders H1 WAR for next pass

    // layer 3: (16x64)@(64x16[4]) + b3 -> delta
    {
      f32x4 acc3 = fzero;
      #pragma unroll
      for (int kt = 0; kt < 2; ++kt) {
        short8 a3 = *(const short8*)(wsm + W_H2 + l15 * 144 + kt * 64 + lg * 16);
        short8 bw;
        if (wfrag) bw = wv4[(24 + kt) * 64 + lane];
        else {
          #pragma unroll
          for (int j = 0; j < 8; ++j)
            bw[j] = (l15 < 4) ? f2bf(W3[(kt * 32 + lg * 8 + j) * 4 + l15]) : (short)0;
        }
        acc3 = __builtin_amdgcn_mfma_f32_16x16x32_bf16(a3, bw, acc3, 0, 0, 0);
      }
      if (l15 < 4) {
        #pragma unroll
        for (int j = 0; j < 4; ++j)
          *(float*)(wsm + W_D + (t * 16 + lg * 4 + j) * 20 + l15 * 4) = acc3[j] + bias3;
      }
    }
  }
  __syncthreads();   // delta visible
}

// ---------------- hot kernel (round-11-identical) ----------------
__global__ __launch_bounds__(256, 2) void MatrixMLP_54047868453544_kernel(
    const float* __restrict__ x,
    const float* __restrict__ W1, const float* __restrict__ b1,
    const float* __restrict__ W2, const float* __restrict__ b2,
    const float* __restrict__ W3, const float* __restrict__ b3,
    const short* __restrict__ wfrag,
    float* __restrict__ out, int Bn)
{
  __shared__ __align__(16) unsigned char smem[SMEM_SZ];
  const int tid  = threadIdx.x;
  const int lane = tid & 63;
  const int wv   = tid >> 6;
  const int l15  = lane & 15;
  const int lg   = lane >> 4;
  unsigned char* wsm = smem + wv * W_SZ;
  const long long g = (long long)blockIdx.x * 256 + wv * 64 + lane;

  // ---- load row (1 row/lane) ----
  float xf[20];
  if (g < Bn) {
    const float* xr = x + g * 20;
    #pragma unroll
    for (int i = 0; i < 5; ++i) {
      f32x4 v = *(const f32x4*)(xr + i * 4);
      xf[i*4+0] = v[0]; xf[i*4+1] = v[1]; xf[i*4+2] = v[2]; xf[i*4+3] = v[3];
    }
  } else {
    #pragma unroll
    for (int i = 0; i < 20; ++i) xf[i] = 0.0f;
  }

  // ---- f32 Cramer solve with safety guard (H[i][j] = x[j*4+i]) ----
  float xls[4];
  {
    float a00 = xf[0], a01 = xf[4], a02 = xf[8],  a03 = xf[12];
    float a10 = xf[1], a11 = xf[5], a12 = xf[9],  a13 = xf[13];
    float a20 = xf[2], a21 = xf[6], a22 = xf[10], a23 = xf[14];
    float a30 = xf[3], a31 = xf[7], a32 = xf[11], a33 = xf[15];
    float y0 = xf[16], y1 = xf[17], y2 = xf[18], y3 = xf[19];

    float s0 = a00*a11 - a10*a01, s1 = a00*a12 - a10*a02, s2 = a00*a13 - a10*a03;
    float s3 = a01*a12 - a11*a02, s4 = a01*a13 - a11*a03, s5 = a02*a13 - a12*a03;
    float c0 = a20*a31 - a30*a21, c1 = a20*a32 - a30*a22, c2 = a20*a33 - a30*a23;
    float c3 = a21*a32 - a31*a22, c4 = a21*a33 - a31*a23, c5 = a22*a33 - a32*a23;
    float det = s0*c5 - s1*c4 + s2*c3 + s3*c2 - s4*c1 + s5*c0;

    float T = a00*a00 + a01*a01 + a02*a02 + a03*a03
            + a10*a10 + a11*a11 + a12*a12 + a13*a13
            + a20*a20 + a21*a21 + a22*a22 + a23*a23
            + a30*a30 + a31*a31 + a32*a32 + a33*a33;

    float xd0 = 0.0f, xd1 = 0.0f, xd2 = 0.0f, xd3 = 0.0f;
    if (__builtin_fabsf(det) > GUARD_THETA * T * T) {
      float rdet = 1.0f / det;
      {
        float q0 =   a11*c5 - a12*c4 + a13*c3;
        float q1 = -(a01*c5 - a02*c4 + a03*c3);
        float q2 =   a31*s5 - a32*s4 + a33*s3;
        float q3 = -(a21*s5 - a22*s4 + a23*s3);
        xd0 = rdet * (q0*y0 + q1*y1 + q2*y2 + q3*y3);
      }
      {
        float q0 = -(a10*c5 - a12*c2 + a13*c1);
        float q1 =   a00*c5 - a02*c2 + a03*c1;
        float q2 = -(a30*s5 - a32*s2 + a33*s1);
        float q3 =   a20*s5 - a22*s2 + a23*s1;
        xd1 = rdet * (q0*y0 + q1*y1 + q2*y2 + q3*y3);
      }
      {
        float q0 =   a10*c4 - a11*c2 + a13*c0;
        float q1 = -(a00*c4 - a01*c2 + a03*c0);
        float q2 =   a30*s4 - a31*s2 + a33*s0;
        float q3 = -(a20*s4 - a21*s2 + a23*s0);
        xd2 = rdet * (q0*y0 + q1*y1 + q2*y2 + q3*y3);
      }
      {
        float q0 = -(a10*c3 - a11*c1 + a12*c0);
        float q1 =   a00*c3 - a01*c1 + a02*c0;
        float q2 = -(a30*s3 - a31*s1 + a32*s0);
        float q3 =   a20*s3 - a21*s1 + a22*s0;
        xd3 = rdet * (q0*y0 + q1*y1 + q2*y2 + q3*y3);
      }
    }
    // unsafe lanes keep xd=0: placeholder, overwritten by repair kernel

    float xdv[4] = {xd0, xd1, xd2, xd3};
    short rowbuf[32];
    #pragma unroll
    for (int i = 0; i < 20; ++i) rowbuf[i] = f2bf(xf[i]);
    #pragma unroll
    for (int i = 0; i < 4; ++i) {
      float v = xdv[i];
      if (v != v) v = 0.0f;
      v = fminf(fmaxf(v, 0.0f), 1.0f);
      xls[i] = v;
      rowbuf[20 + i] = f2bf(v);
    }
    #pragma unroll
    for (int i = 24; i < 32; ++i) rowbuf[i] = 0;
    short8* dst = (short8*)(wsm + W_A + lane * 80);
    #pragma unroll
    for (int i = 0; i < 4; ++i) dst[i] = *(short8*)(rowbuf + i * 8);
  }

  // ---- MFMA MLP (barrier-synced shared body) ----
  mlp_wave(wsm, lane, l15, lg, wfrag, W1, b1, W2, b2, W3, b3);

  // ---- epilogue: out = clip(x_ls + delta, 0, 1) ----
  if (g < Bn) {
    const unsigned char* dl = wsm + W_D + lane * 20;
    f32x4 o;
    #pragma unroll
    for (int c = 0; c < 4; ++c) {
      float v = xls[c] + *(const float*)(dl + c * 4);
      o[c] = fminf(fmaxf(v, 0.0f), 1.0f);
    }
    *(f32x4*)(out + g * 4) = o;
  }
}

// ---------------- repair kernel (parallel buckets; barrier-safe) ------------
__global__ __launch_bounds__(256) void repair_rows(
    const float* __restrict__ x,
    const float* __restrict__ W1, const float* __restrict__ b1,
    const float* __restrict__ W2, const float* __restrict__ b2,
    const float* __restrict__ W3, const float* __restrict__ b3,
    const short* __restrict__ wfrag,
    float* __restrict__ out, int Bn,
    const int* __restrict__ wl_cnt, const int* __restrict__ wl_list,
    int use_wl, int nbuck, int cap)
{
  __shared__ __align__(16) unsigned char smem[SMEM_SZ];
  const int tid  = threadIdx.x;
  const int lane = tid & 63;
  const int wv   = tid >> 6;
  const int l15  = lane & 15;
  const int lg   = lane >> 4;
  unsigned char* wsm = smem + wv * W_SZ;

  // parallel bucket assignment: block -> (bucket, sub); all uniform per block
  const int bucket = use_wl ? ((int)blockIdx.x % nbuck) : 0;
  const int sub    = use_wl ? ((int)blockIdx.x / nbuck) : (int)blockIdx.x;
  const int nsub   = use_wl ? ((int)gridDim.x / nbuck)  : (int)gridDim.x;
  const int cnt = use_wl ? wl_cnt[bucket * 32] : Bn;
  const int* lst = wl_list + (size_t)bucket * cap;

  for (long long blk0 = (long long)sub * 256; blk0 < cnt;
       blk0 += (long long)nsub * 256) {
    const long long idx = blk0 + tid;
    int g = -1;
    if (idx < cnt) g = use_wl ? lst[idx] : (int)idx;

    float xf[20];
    if (g >= 0) {
      const float* xr = x + (long long)g * 20;
      #pragma unroll
      for (int i = 0; i < 5; ++i) {
        f32x4 v = *(const f32x4*)(xr + i * 4);
        xf[i*4+0] = v[0]; xf[i*4+1] = v[1]; xf[i*4+2] = v[2]; xf[i*4+3] = v[3];
      }
    } else {
      #pragma unroll
      for (int i = 0; i < 20; ++i) xf[i] = 0.0f;
    }

    if (!use_wl && g >= 0) {
      // fallback scan: keep only rows failing the hot guard
      float a00 = xf[0], a01 = xf[4], a02 = xf[8],  a03 = xf[12];
      float a10 = xf[1], a11 = xf[5], a12 = xf[9],  a13 = xf[13];
      float a20 = xf[2], a21 = xf[6], a22 = xf[10], a23 = xf[14];
      float a30 = xf[3], a31 = xf[7], a32 = xf[11], a33 = xf[15];
      float s0 = a00*a11 - a10*a01, s1 = a00*a12 - a10*a02, s2 = a00*a13 - a10*a03;
      float s3 = a01*a12 - a11*a02, s4 = a01*a13 - a11*a03, s5 = a02*a13 - a12*a03;
      float c0 = a20*a31 - a30*a21, c1 = a20*a32 - a30*a22, c2 = a20*a33 - a30*a23;
      float c3 = a21*a32 - a31*a22, c4 = a21*a33 - a31*a23, c5 = a22*a33 - a32*a23;
      float det = s0*c5 - s1*c4 + s2*c3 + s3*c2 - s4*c1 + s5*c0;
      float T = a00*a00 + a01*a01 + a02*a02 + a03*a03
              + a10*a10 + a11*a11 + a12*a12 + a13*a13
              + a20*a20 + a21*a21 + a22*a22 + a23*a23
              + a30*a30 + a31*a31 + a32*a32 + a33*a33;
      if (__builtin_fabsf(det) > GUARD_THETA * T * T) g = -1;
    }

    // ---- f64 Jacobi eigensolve of G = H^T H + jax rcond truncation ----
    double G[4][4], V[4][4], rhs[4];
    #pragma unroll
    for (int p = 0; p < 4; ++p) {
      #pragma unroll
      for (int q = 0; q < 4; ++q) {
        double s = 0.0;
        #pragma unroll
        for (int k = 0; k < 4; ++k)
          s += (double)xf[p * 4 + k] * (double)xf[q * 4 + k];
        G[p][q] = s;
        V[p][q] = (p == q) ? 1.0 : 0.0;
      }
      double s = 0.0;
      #pragma unroll
      for (int k = 0; k < 4; ++k) s += (double)xf[p * 4 + k] * (double)xf[16 + k];
      rhs[p] = s;
    }
    #pragma unroll 1      // rolled: serial chain anyway; cuts VGPR/code bloat
    for (int sweep = 0; sweep < 6; ++sweep) {
      #pragma unroll
      for (int pq = 0; pq < 6; ++pq) {
        constexpr int PP[6] = {0, 0, 0, 1, 1, 2};
        constexpr int QQ[6] = {1, 2, 3, 2, 3, 3};
        const int p = PP[pq], q = QQ[pq];
        double apq = G[p][q];
        double c, s;
        if (apq != 0.0) {
          double tau = (G[q][q] - G[p][p]) / (2.0 * apq);
          double t = (tau >= 0.0 ? 1.0 : -1.0) / (fabs(tau) + sqrt(1.0 + tau * tau));
          c = 1.0 / sqrt(1.0 + t * t);
          s = t * c;
        } else { c = 1.0; s = 0.0; }
        #pragma unroll
        for (int k = 0; k < 4; ++k) {
          double gpk = G[p][k], gqk = G[q][k];
          G[p][k] = c * gpk - s * gqk;
          G[q][k] = s * gpk + c * gqk;
        }
        #pragma unroll
        for (int k = 0; k < 4; ++k) {
          double gkp = G[k][p], gkq = G[k][q];
          G[k][p] = c * gkp - s * gkq;
          G[k][q] = s * gkp + c * gkq;
        }
        #pragma unroll
        for (int k = 0; k < 4; ++k) {
          double vkp = V[k][p], vkq = V[k][q];
          V[k][p] = c * vkp - s * vkq;
          V[k][q] = s * vkp + c * vkq;
        }
      }
    }
    double lam[4] = {G[0][0], G[1][1], G[2][2], G[3][3]};
    double lmax = fmax(fmax(lam[0], lam[1]), fmax(lam[2], lam[3]));
    lmax = fmax(lmax, 0.0);
    const double cut = 2.27373675443232e-11 * lmax;  // (4.7683716e-6)^2
    double xd0 = 0.0, xd1 = 0.0, xd2 = 0.0, xd3 = 0.0;
    #pragma unroll
    for (int k = 0; k < 4; ++k) {
      if (lam[k] > cut && lam[k] > 0.0) {
        double coef = (V[0][k] * rhs[0] + V[1][k] * rhs[1] +
                       V[2][k] * rhs[2] + V[3][k] * rhs[3]) / lam[k];
        xd0 += V[0][k] * coef;
        xd1 += V[1][k] * coef;
        xd2 += V[2][k] * coef;
        xd3 += V[3][k] * coef;
      }
    }

    float xls[4];
    {
      double xd[4] = {xd0, xd1, xd2, xd3};
      short rowbuf[32];
      #pragma unroll
      for (int i = 0; i < 20; ++i) rowbuf[i] = f2bf(xf[i]);
      #pragma unroll
      for (int i = 0; i < 4; ++i) {
        float v = (float)xd[i];
        if (v != v) v = 0.0f;
        v = fminf(fmaxf(v, 0.0f), 1.0f);
        xls[i] = v;
        rowbuf[20 + i] = f2bf(v);
      }
      #pragma unroll
      for (int i = 24; i < 32; ++i) rowbuf[i] = 0;
      short8* dst = (short8*)(wsm + W_A + lane * 80);
      #pragma unroll
      for (int i = 0; i < 4; ++i) dst[i] = *(short8*)(rowbuf + i * 8);
    }

    mlp_wave(wsm, lane, l15, lg, wfrag, W1, b1, W2, b2, W3, b3);

    if (g >= 0) {
      const unsigned char* dl = wsm + W_D + lane * 20;
      f32x4 o;
      #pragma unroll
      for (int c = 0; c < 4; ++c) {
        float v = xls[c] + *(const float*)(dl + c * 4);
        o[c] = fminf(fmaxf(v, 0.0f), 1.0f);
      }
      *(f32x4*)(out + (long long)g * 4) = o;
    }
  }
}

extern "C" void kernel_launch(void* const* d_in, const int* in_sizes, int n_in,
                              void* d_out, int out_size, void* d_ws, size_t ws_size,
                              hipStream_t stream) {
  (void)n_in;
  const float* x  = (const float*)d_in[0];
  const float* W1 = (const float*)d_in[1];
  const float* b1 = (const float*)d_in[2];
  const float* W2 = (const float*)d_in[3];
  const float* b2 = (const float*)d_in[4];
  const float* W3 = (const float*)d_in[5];
  const float* b3 = (const float*)d_in[6];
  float* out = (float*)d_out;
  const int Bn = in_sizes[0] / 20;
  const int nblk = (Bn + 255) / 256;

  short* wfrag = nullptr;
  int* wl_cnt = nullptr;
  int* wl_list = nullptr;
  int use_wl = 0, nbuck = 1, cap = 0;
  if (ws_size >= (size_t)WFRAG_BYTES) wfrag = (short*)d_ws;
  {
    int cap32 = 256 * ((nblk + NBUCK - 1) / NBUCK);
    int cap1  = 256 * nblk;
    if (ws_size >= (size_t)WL_LIST_OFF + 4ull * NBUCK * (size_t)cap32) {
      nbuck = NBUCK; cap = cap32; use_wl = 1;
    } else if (ws_size >= (size_t)WL_LIST_OFF + 4ull * (size_t)cap1) {
      nbuck = 1; cap = cap1; use_wl = 1;
    }
    if (use_wl) {
      wl_cnt  = (int*)((char*)d_ws + WL_CNT_OFF);
      wl_list = (int*)((char*)d_ws + WL_LIST_OFF);
    }
  }

  (void)hipGetLastError();
  if (wfrag) pack_w<<<7, 256, 0, stream>>>(W1, W2, W3, wfrag, wl_cnt);

  if (use_wl)
    classify<<<nblk, 256, 0, stream>>>(x, Bn, wl_cnt, wl_list, nbuck, cap);

  MatrixMLP_54047868453544_kernel<<<nblk, 256, 0, stream>>>(
      x, W1, b1, W2, b2, W3, b3, wfrag, out, Bn);

  // RBLK must be a multiple of nbuck for the parallel-bucket mapping
  const int rblk = use_wl ? (nbuck * (RBLK / NBUCK)) : RBLK;
  repair_rows<<<rblk, 256, 0, stream>>>(x, W1, b1, W2, b2, W3, b3, wfrag,
                                        out, Bn, wl_cnt, wl_list,
                                        use_wl, nbuck, cap);
  hipError_t e = hipGetLastError();
  if (e != hipSuccess) {
    int byte = 0x40 + ((int)e & 63);
    hipMemsetAsync(d_out, byte, (size_t)out_size * sizeof(float), stream);
  }
}

// Round 13
// 67.817 us; speedup vs baseline: 12.2356x; 1.7875x over previous
//
#include <hip/hip_runtime.h>

// MatrixMLP round 13: slim the hot kernel to kill the 174MB phantom writes.
//  - Hot kernel: NO fallback weight-gather branches (wfrag required; template
//    mlp_wave<WF>), NO local arrays (named f32x4 / short8 / scalars only).
//  - classify / pack_w / repair structure from round 12 (repair ~20us).
//  - ws-too-small fallback: repair_rows full-scan computes ALL rows via the
//    f64 Jacobi path (round-4-proven) -- slow but correct, never expected.

typedef __attribute__((ext_vector_type(8))) short short8;
typedef __attribute__((ext_vector_type(4))) float f32x4;

__device__ __forceinline__ short f2bf(float f) {
  unsigned int u = __float_as_uint(f);
  u += 0x7fffu + ((u >> 16) & 1u);
  return (short)(u >> 16);
}
__device__ __forceinline__ float cl01(float v) {
  if (v != v) v = 0.0f;
  return fminf(fmaxf(v, 0.0f), 1.0f);
}

#define GUARD_THETA 1.0e-4f
#define WFRAG_BYTES 26624        // 26 frags * 64 lanes * 16 B
#define WL_CNT_OFF  26624        // 32 counters, stride 32 ints (128 B)
#define WL_LIST_OFF 30720
#define NBUCK 32
#define RBLK 256

// ---- per-wave LDS chunk (bytes) ----
#define W_A    0        // 64 rows * 80 B
#define W_H1   5120     // 16 rows * 272 B
#define W_H2   9472     // 16 rows * 144 B
#define W_D    11776    // 64 rows * 20 B
#define W_SZ   13056
#define SMEM_SZ (4 * W_SZ)   // 52224 B -> 3 blocks/CU

// ---------------- weight fragment pre-pack (+ counter reset) ----------------
__global__ void pack_w(const float* __restrict__ W1, const float* __restrict__ W2,
                       const float* __restrict__ W3, short* __restrict__ ws,
                       int* __restrict__ wl_cnt)
{
  if (wl_cnt && blockIdx.x == 0 && threadIdx.x < NBUCK)
    wl_cnt[threadIdx.x * 32] = 0;
  int t = blockIdx.x * 256 + threadIdx.x;
  if (t >= 26 * 64) return;
  int fid = t >> 6, lane = t & 63, l15 = lane & 15, lg = lane >> 4;
  short8 v;
  if (fid < 8) {
    int col = fid * 16 + l15;
    #pragma unroll
    for (int j = 0; j < 8; ++j) {
      int k = lg * 8 + j;
      v[j] = (k < 24) ? f2bf(W1[k * 128 + col]) : (short)0;
    }
  } else if (fid < 24) {
    int q = fid - 8, kt = q >> 2, nt = q & 3, col = nt * 16 + l15;
    #pragma unroll
    for (int j = 0; j < 8; ++j)
      v[j] = f2bf(W2[(kt * 32 + lg * 8 + j) * 64 + col]);
  } else {
    int kt = fid - 24;
    #pragma unroll
    for (int j = 0; j < 8; ++j)
      v[j] = (l15 < 4) ? f2bf(W3[(kt * 32 + lg * 8 + j) * 4 + l15]) : (short)0;
  }
  ((short8*)ws)[t] = v;
}

// ---------------- classify: bucketed repair worklist ----------------
__global__ __launch_bounds__(256) void classify(
    const float* __restrict__ x, int Bn,
    int* __restrict__ wl_cnt, int* __restrict__ wl_list,
    int nbuck, int cap)
{
  const int lane = threadIdx.x & 63;
  const long long g = (long long)blockIdx.x * 256 + threadIdx.x;
  bool unsafe_row = false;
  if (g < Bn) {
    const f32x4* xr = (const f32x4*)(x + g * 20);
    f32x4 v0 = xr[0], v1 = xr[1], v2 = xr[2], v3 = xr[3];
    float a00 = v0[0], a10 = v0[1], a20 = v0[2], a30 = v0[3];
    float a01 = v1[0], a11 = v1[1], a21 = v1[2], a31 = v1[3];
    float a02 = v2[0], a12 = v2[1], a22 = v2[2], a32 = v2[3];
    float a03 = v3[0], a13 = v3[1], a23 = v3[2], a33 = v3[3];
    float s0 = a00*a11 - a10*a01, s1 = a00*a12 - a10*a02, s2 = a00*a13 - a10*a03;
    float s3 = a01*a12 - a11*a02, s4 = a01*a13 - a11*a03, s5 = a02*a13 - a12*a03;
    float c0 = a20*a31 - a30*a21, c1 = a20*a32 - a30*a22, c2 = a20*a33 - a30*a23;
    float c3 = a21*a32 - a31*a22, c4 = a21*a33 - a31*a23, c5 = a22*a33 - a32*a23;
    float det = s0*c5 - s1*c4 + s2*c3 + s3*c2 - s4*c1 + s5*c0;
    float T = a00*a00 + a01*a01 + a02*a02 + a03*a03
            + a10*a10 + a11*a11 + a12*a12 + a13*a13
            + a20*a20 + a21*a21 + a22*a22 + a23*a23
            + a30*a30 + a31*a31 + a32*a32 + a33*a33;
    unsafe_row = !(__builtin_fabsf(det) > GUARD_THETA * 1.004f * T * T);
  }
  unsigned long long m = __ballot(unsafe_row);
  if (m) {
    const int bucket = blockIdx.x % nbuck;
    int leader = (int)__builtin_ctzll(m);
    int base = 0;
    if (lane == leader)
      base = atomicAdd(&wl_cnt[bucket * 32], (int)__builtin_popcountll(m));
    base = __shfl(base, leader, 64);
    if (unsafe_row) {
      int lt = (int)__builtin_popcountll(m & ((1ull << lane) - 1ull));
      wl_list[(size_t)bucket * cap + base + lt] = (int)g;
    }
  }
}

// ---------------- shared MFMA MLP body (barrier-synced) ----------------
template <bool WF>
__device__ __forceinline__ void mlp_wave(
    unsigned char* wsm, int lane, int l15, int lg,
    const short8* __restrict__ wv4,
    const float* __restrict__ W1, const float* __restrict__ W2,
    const float* __restrict__ W3,
    const float* __restrict__ b1, const float* __restrict__ b2,
    const float* __restrict__ b3)
{
  const f32x4 fzero = {0.0f, 0.0f, 0.0f, 0.0f};

  short8 bf1[8];
  if constexpr (WF) {
    #pragma unroll
    for (int nt = 0; nt < 8; ++nt) bf1[nt] = wv4[nt * 64 + lane];
  } else {
    #pragma unroll
    for (int nt = 0; nt < 8; ++nt) {
      int col = nt * 16 + l15;
      #pragma unroll
      for (int j = 0; j < 8; ++j) {
        int k = lg * 8 + j;
        bf1[nt][j] = (k < 24) ? f2bf(W1[k * 128 + col]) : (short)0;
      }
    }
  }
  float bias1[8], bias2[4], bias3;
  #pragma unroll
  for (int nt = 0; nt < 8; ++nt) bias1[nt] = b1[nt * 16 + l15];
  #pragma unroll
  for (int nt = 0; nt < 4; ++nt) bias2[nt] = b2[nt * 16 + l15];
  bias3 = b3[l15 & 3];

  __syncthreads();   // A-rows visible

  for (int t = 0; t < 4; ++t) {
    // layer 1: (16x32)@(32x128) + b1, ReLU -> H1 tile
    {
      short8 a = *(const short8*)(wsm + W_A + (t * 16 + l15) * 80 + lg * 16);
      f32x4 acc[8];
      #pragma unroll
      for (int nt = 0; nt < 8; ++nt)
        acc[nt] = __builtin_amdgcn_mfma_f32_16x16x32_bf16(a, bf1[nt], fzero, 0, 0, 0);
      #pragma unroll
      for (int nt = 0; nt < 8; ++nt) {
        #pragma unroll
        for (int j = 0; j < 4; ++j) {
          float h = acc[nt][j] + bias1[nt];
          h = h > 0.0f ? h : 0.0f;
          *(short*)(wsm + W_H1 + (lg * 4 + j) * 272 + (nt * 16 + l15) * 2) = f2bf(h);
        }
      }
    }
    __syncthreads();

    // layer 2: (16x128)@(128x64) + b2, ReLU -> H2 tile
    {
      f32x4 acc2[4] = {fzero, fzero, fzero, fzero};
      #pragma unroll
      for (int kt = 0; kt < 4; ++kt) {
        short8 a2 = *(const short8*)(wsm + W_H1 + l15 * 272 + kt * 64 + lg * 16);
        #pragma unroll
        for (int nt = 0; nt < 4; ++nt) {
          short8 bw;
          if constexpr (WF) {
            bw = wv4[(8 + kt * 4 + nt) * 64 + lane];
          } else {
            int col = nt * 16 + l15;
            #pragma unroll
            for (int j = 0; j < 8; ++j)
              bw[j] = f2bf(W2[(kt * 32 + lg * 8 + j) * 64 + col]);
          }
          acc2[nt] = __builtin_amdgcn_mfma_f32_16x16x32_bf16(a2, bw, acc2[nt], 0, 0, 0);
        }
      }
      #pragma unroll
      for (int nt = 0; nt < 4; ++nt) {
        #pragma unroll
        for (int j = 0; j < 4; ++j) {
          float h = acc2[nt][j] + bias2[nt];
          h = h > 0.0f ? h : 0.0f;
          *(short*)(wsm + W_H2 + (lg * 4 + j) * 144 + (nt * 16 + l15) * 2) = f2bf(h);
        }
      }
    }
    __syncthreads();

    // layer 3: (16x64)@(64x16[4]) + b3 -> delta
    {
      f32x4 acc3 = fzero;
      #pragma unroll
      for (int kt = 0; kt < 2; ++kt) {
        short8 a3 = *(const short8*)(wsm + W_H2 + l15 * 144 + kt * 64 + lg * 16);
        short8 bw;
        if constexpr (WF) {
          bw = wv4[(24 + kt) * 64 + lane];
        } else {
          #pragma unroll
          for (int j = 0; j < 8; ++j)
            bw[j] = (l15 < 4) ? f2bf(W3[(kt * 32 + lg * 8 + j) * 4 + l15]) : (short)0;
        }
        acc3 = __builtin_amdgcn_mfma_f32_16x16x32_bf16(a3, bw, acc3, 0, 0, 0);
      }
      if (l15 < 4) {
        #pragma unroll
        for (int j = 0; j < 4; ++j)
          *(float*)(wsm + W_D + (t * 16 + lg * 4 + j) * 20 + l15 * 4) = acc3[j] + bias3;
      }
    }
  }
  __syncthreads();   // delta visible
}

// ---------------- hot kernel (slim: no fallbacks, no local arrays) ----------
__global__ __launch_bounds__(256, 2) void MatrixMLP_54047868453544_kernel(
    const float* __restrict__ x,
    const float* __restrict__ b1, const float* __restrict__ b2,
    const float* __restrict__ b3,
    const short* __restrict__ wfrag,
    float* __restrict__ out, int Bn)
{
  __shared__ __align__(16) unsigned char smem[SMEM_SZ];
  const int tid  = threadIdx.x;
  const int lane = tid & 63;
  const int wv   = tid >> 6;
  const int l15  = lane & 15;
  const int lg   = lane >> 4;
  unsigned char* wsm = smem + wv * W_SZ;
  const long long g = (long long)blockIdx.x * 256 + wv * 64 + lane;
  const f32x4 fzero = {0.0f, 0.0f, 0.0f, 0.0f};

  // ---- load row as named vectors (80 B rows are 16-B aligned) ----
  f32x4 v0 = fzero, v1 = fzero, v2 = fzero, v3 = fzero, v4 = fzero;
  if (g < Bn) {
    const f32x4* xr = (const f32x4*)(x + g * 20);
    v0 = xr[0]; v1 = xr[1]; v2 = xr[2]; v3 = xr[3]; v4 = xr[4];
  }

  // ---- f32 Cramer solve with safety guard; all named scalars ----
  float a00 = v0[0], a10 = v0[1], a20 = v0[2], a30 = v0[3];
  float a01 = v1[0], a11 = v1[1], a21 = v1[2], a31 = v1[3];
  float a02 = v2[0], a12 = v2[1], a22 = v2[2], a32 = v2[3];
  float a03 = v3[0], a13 = v3[1], a23 = v3[2], a33 = v3[3];
  float y0 = v4[0], y1 = v4[1], y2 = v4[2], y3 = v4[3];

  float s0 = a00*a11 - a10*a01, s1 = a00*a12 - a10*a02, s2 = a00*a13 - a10*a03;
  float s3 = a01*a12 - a11*a02, s4 = a01*a13 - a11*a03, s5 = a02*a13 - a12*a03;
  float c0 = a20*a31 - a30*a21, c1 = a20*a32 - a30*a22, c2 = a20*a33 - a30*a23;
  float c3 = a21*a32 - a31*a22, c4 = a21*a33 - a31*a23, c5 = a22*a33 - a32*a23;
  float det = s0*c5 - s1*c4 + s2*c3 + s3*c2 - s4*c1 + s5*c0;
  float T = a00*a00 + a01*a01 + a02*a02 + a03*a03
          + a10*a10 + a11*a11 + a12*a12 + a13*a13
          + a20*a20 + a21*a21 + a22*a22 + a23*a23
          + a30*a30 + a31*a31 + a32*a32 + a33*a33;

  float xd0 = 0.0f, xd1 = 0.0f, xd2 = 0.0f, xd3 = 0.0f;
  if (__builtin_fabsf(det) > GUARD_THETA * T * T) {
    float rdet = 1.0f / det;
    xd0 = rdet * ((  a11*c5 - a12*c4 + a13*c3) * y0 +
                  (-(a01*c5 - a02*c4 + a03*c3)) * y1 +
                  (  a31*s5 - a32*s4 + a33*s3) * y2 +
                  (-(a21*s5 - a22*s4 + a23*s3)) * y3);
    xd1 = rdet * ((-(a10*c5 - a12*c2 + a13*c1)) * y0 +
                  (  a00*c5 - a02*c2 + a03*c1) * y1 +
                  (-(a30*s5 - a32*s2 + a33*s1)) * y2 +
                  (  a20*s5 - a22*s2 + a23*s1) * y3);
    xd2 = rdet * ((  a10*c4 - a11*c2 + a13*c0) * y0 +
                  (-(a00*c4 - a01*c2 + a03*c0)) * y1 +
                  (  a30*s4 - a31*s2 + a33*s0) * y2 +
                  (-(a20*s4 - a21*s2 + a23*s0)) * y3);
    xd3 = rdet * ((-(a10*c3 - a11*c1 + a12*c0)) * y0 +
                  (  a00*c3 - a01*c1 + a02*c0) * y1 +
                  (-(a30*s3 - a31*s1 + a32*s0)) * y2 +
                  (  a20*s3 - a21*s1 + a22*s0) * y3);
  }
  // unsafe lanes keep xd=0: placeholder, overwritten by repair kernel

  const float xls0 = cl01(xd0), xls1 = cl01(xd1);
  const float xls2 = cl01(xd2), xls3 = cl01(xd3);

  // ---- A-row as named short8 vectors (no local arrays) ----
  short8 r0 = { f2bf(v0[0]), f2bf(v0[1]), f2bf(v0[2]), f2bf(v0[3]),
                f2bf(v1[0]), f2bf(v1[1]), f2bf(v1[2]), f2bf(v1[3]) };
  short8 r1 = { f2bf(v2[0]), f2bf(v2[1]), f2bf(v2[2]), f2bf(v2[3]),
                f2bf(v3[0]), f2bf(v3[1]), f2bf(v3[2]), f2bf(v3[3]) };
  short8 r2 = { f2bf(v4[0]), f2bf(v4[1]), f2bf(v4[2]), f2bf(v4[3]),
                f2bf(xls0),  f2bf(xls1),  f2bf(xls2),  f2bf(xls3) };
  short8 r3 = { 0, 0, 0, 0, 0, 0, 0, 0 };
  {
    short8* dst = (short8*)(wsm + W_A + lane * 80);
    dst[0] = r0; dst[1] = r1; dst[2] = r2; dst[3] = r3;
  }

  // ---- MFMA MLP (wfrag-only instantiation) ----
  mlp_wave<true>(wsm, lane, l15, lg, (const short8*)wfrag,
                 nullptr, nullptr, nullptr, b1, b2, b3);

  // ---- epilogue: out = clip(x_ls + delta, 0, 1) ----
  if (g < Bn) {
    const float* dl = (const float*)(wsm + W_D + lane * 20);
    f32x4 o = { fminf(fmaxf(xls0 + dl[0], 0.0f), 1.0f),
                fminf(fmaxf(xls1 + dl[1], 0.0f), 1.0f),
                fminf(fmaxf(xls2 + dl[2], 0.0f), 1.0f),
                fminf(fmaxf(xls3 + dl[3], 0.0f), 1.0f) };
    *(f32x4*)(out + g * 4) = o;
  }
}

// ---------------- repair kernel (parallel buckets / full-scan fallback) -----
__global__ __launch_bounds__(256) void repair_rows(
    const float* __restrict__ x,
    const float* __restrict__ W1, const float* __restrict__ b1,
    const float* __restrict__ W2, const float* __restrict__ b2,
    const float* __restrict__ W3, const float* __restrict__ b3,
    const short* __restrict__ wfrag,
    float* __restrict__ out, int Bn,
    const int* __restrict__ wl_cnt, const int* __restrict__ wl_list,
    int use_wl, int nbuck, int cap, int write_all)
{
  __shared__ __align__(16) unsigned char smem[SMEM_SZ];
  const int tid  = threadIdx.x;
  const int lane = tid & 63;
  const int wv   = tid >> 6;
  const int l15  = lane & 15;
  const int lg   = lane >> 4;
  unsigned char* wsm = smem + wv * W_SZ;

  const int bucket = use_wl ? ((int)blockIdx.x % nbuck) : 0;
  const int sub    = use_wl ? ((int)blockIdx.x / nbuck) : (int)blockIdx.x;
  const int nsub   = use_wl ? ((int)gridDim.x / nbuck)  : (int)gridDim.x;
  const int cnt = use_wl ? wl_cnt[bucket * 32] : Bn;
  const int* lst = wl_list + (size_t)bucket * cap;

  for (long long blk0 = (long long)sub * 256; blk0 < cnt;
       blk0 += (long long)nsub * 256) {
    const long long idx = blk0 + tid;
    int g = -1;
    if (idx < cnt) g = use_wl ? lst[idx] : (int)idx;

    float xf[20];
    if (g >= 0) {
      const float* xr = x + (long long)g * 20;
      #pragma unroll
      for (int i = 0; i < 5; ++i) {
        f32x4 v = *(const f32x4*)(xr + i * 4);
        xf[i*4+0] = v[0]; xf[i*4+1] = v[1]; xf[i*4+2] = v[2]; xf[i*4+3] = v[3];
      }
    } else {
      #pragma unroll
      for (int i = 0; i < 20; ++i) xf[i] = 0.0f;
    }

    if (!use_wl && !write_all && g >= 0) {
      // scan fallback with hot kernel present: keep only guard-failing rows
      float a00 = xf[0], a01 = xf[4], a02 = xf[8],  a03 = xf[12];
      float a10 = xf[1], a11 = xf[5], a12 = xf[9],  a13 = xf[13];
      float a20 = xf[2], a21 = xf[6], a22 = xf[10], a23 = xf[14];
      float a30 = xf[3], a31 = xf[7], a32 = xf[11], a33 = xf[15];
      float s0 = a00*a11 - a10*a01, s1 = a00*a12 - a10*a02, s2 = a00*a13 - a10*a03;
      float s3 = a01*a12 - a11*a02, s4 = a01*a13 - a11*a03, s5 = a02*a13 - a12*a03;
      float c0 = a20*a31 - a30*a21, c1 = a20*a32 - a30*a22, c2 = a20*a33 - a30*a23;
      float c3 = a21*a32 - a31*a22, c4 = a21*a33 - a31*a23, c5 = a22*a33 - a32*a23;
      float det = s0*c5 - s1*c4 + s2*c3 + s3*c2 - s4*c1 + s5*c0;
      float T = a00*a00 + a01*a01 + a02*a02 + a03*a03
              + a10*a10 + a11*a11 + a12*a12 + a13*a13
              + a20*a20 + a21*a21 + a22*a22 + a23*a23
              + a30*a30 + a31*a31 + a32*a32 + a33*a33;
      if (__builtin_fabsf(det) > GUARD_THETA * 1.004f * T * T) g = -1;
    }

    // ---- f64 Jacobi eigensolve of G = H^T H + jax rcond truncation ----
    double G[4][4], V[4][4], rhs[4];
    #pragma unroll
    for (int p = 0; p < 4; ++p) {
      #pragma unroll
      for (int q = 0; q < 4; ++q) {
        double s = 0.0;
        #pragma unroll
        for (int k = 0; k < 4; ++k)
          s += (double)xf[p * 4 + k] * (double)xf[q * 4 + k];
        G[p][q] = s;
        V[p][q] = (p == q) ? 1.0 : 0.0;
      }
      double s = 0.0;
      #pragma unroll
      for (int k = 0; k < 4; ++k) s += (double)xf[p * 4 + k] * (double)xf[16 + k];
      rhs[p] = s;
    }
    #pragma unroll 1
    for (int sweep = 0; sweep < 6; ++sweep) {
      #pragma unroll
      for (int pq = 0; pq < 6; ++pq) {
        constexpr int PP[6] = {0, 0, 0, 1, 1, 2};
        constexpr int QQ[6] = {1, 2, 3, 2, 3, 3};
        const int p = PP[pq], q = QQ[pq];
        double apq = G[p][q];
        double c, s;
        if (apq != 0.0) {
          double tau = (G[q][q] - G[p][p]) / (2.0 * apq);
          double t = (tau >= 0.0 ? 1.0 : -1.0) / (fabs(tau) + sqrt(1.0 + tau * tau));
          c = 1.0 / sqrt(1.0 + t * t);
          s = t * c;
        } else { c = 1.0; s = 0.0; }
        #pragma unroll
        for (int k = 0; k < 4; ++k) {
          double gpk = G[p][k], gqk = G[q][k];
          G[p][k] = c * gpk - s * gqk;
          G[q][k] = s * gpk + c * gqk;
        }
        #pragma unroll
        for (int k = 0; k < 4; ++k) {
          double gkp = G[k][p], gkq = G[k][q];
          G[k][p] = c * gkp - s * gkq;
          G[k][q] = s * gkp + c * gkq;
        }
        #pragma unroll
        for (int k = 0; k < 4; ++k) {
          double vkp = V[k][p], vkq = V[k][q];
          V[k][p] = c * vkp - s * vkq;
          V[k][q] = s * vkp + c * vkq;
        }
      }
    }
    double lam[4] = {G[0][0], G[1][1], G[2][2], G[3][3]};
    double lmax = fmax(fmax(lam[0], lam[1]), fmax(lam[2], lam[3]));
    lmax = fmax(lmax, 0.0);
    const double cut = 2.27373675443232e-11 * lmax;  // (4.7683716e-6)^2
    double xd0 = 0.0, xd1 = 0.0, xd2 = 0.0, xd3 = 0.0;
    #pragma unroll
    for (int k = 0; k < 4; ++k) {
      if (lam[k] > cut && lam[k] > 0.0) {
        double coef = (V[0][k] * rhs[0] + V[1][k] * rhs[1] +
                       V[2][k] * rhs[2] + V[3][k] * rhs[3]) / lam[k];
        xd0 += V[0][k] * coef;
        xd1 += V[1][k] * coef;
        xd2 += V[2][k] * coef;
        xd3 += V[3][k] * coef;
      }
    }

    float xls[4];
    {
      double xd[4] = {xd0, xd1, xd2, xd3};
      short rowbuf[32];
      #pragma unroll
      for (int i = 0; i < 20; ++i) rowbuf[i] = f2bf(xf[i]);
      #pragma unroll
      for (int i = 0; i < 4; ++i) {
        float v = (float)xd[i];
        if (v != v) v = 0.0f;
        v = fminf(fmaxf(v, 0.0f), 1.0f);
        xls[i] = v;
        rowbuf[20 + i] = f2bf(v);
      }
      #pragma unroll
      for (int i = 24; i < 32; ++i) rowbuf[i] = 0;
      short8* dst = (short8*)(wsm + W_A + lane * 80);
      #pragma unroll
      for (int i = 0; i < 4; ++i) dst[i] = *(short8*)(rowbuf + i * 8);
    }

    if (wfrag)
      mlp_wave<true>(wsm, lane, l15, lg, (const short8*)wfrag,
                     W1, W2, W3, b1, b2, b3);
    else
      mlp_wave<false>(wsm, lane, l15, lg, nullptr,
                      W1, W2, W3, b1, b2, b3);

    if (g >= 0) {
      const float* dl = (const float*)(wsm + W_D + lane * 20);
      f32x4 o = { fminf(fmaxf(xls[0] + dl[0], 0.0f), 1.0f),
                  fminf(fmaxf(xls[1] + dl[1], 0.0f), 1.0f),
                  fminf(fmaxf(xls[2] + dl[2], 0.0f), 1.0f),
                  fminf(fmaxf(xls[3] + dl[3], 0.0f), 1.0f) };
      *(f32x4*)(out + (long long)g * 4) = o;
    }
  }
}

extern "C" void kernel_launch(void* const* d_in, const int* in_sizes, int n_in,
                              void* d_out, int out_size, void* d_ws, size_t ws_size,
                              hipStream_t stream) {
  (void)n_in;
  const float* x  = (const float*)d_in[0];
  const float* W1 = (const float*)d_in[1];
  const float* b1 = (const float*)d_in[2];
  const float* W2 = (const float*)d_in[3];
  const float* b2 = (const float*)d_in[4];
  const float* W3 = (const float*)d_in[5];
  const float* b3 = (const float*)d_in[6];
  float* out = (float*)d_out;
  const int Bn = in_sizes[0] / 20;
  const int nblk = (Bn + 255) / 256;

  short* wfrag = nullptr;
  int* wl_cnt = nullptr;
  int* wl_list = nullptr;
  int use_wl = 0, nbuck = 1, cap = 0;
  if (ws_size >= (size_t)WFRAG_BYTES) wfrag = (short*)d_ws;
  {
    int cap32 = 256 * ((nblk + NBUCK - 1) / NBUCK);
    int cap1  = 256 * nblk;
    if (ws_size >= (size_t)WL_LIST_OFF + 4ull * NBUCK * (size_t)cap32) {
      nbuck = NBUCK; cap = cap32; use_wl = 1;
    } else if (ws_size >= (size_t)WL_LIST_OFF + 4ull * (size_t)cap1) {
      nbuck = 1; cap = cap1; use_wl = 1;
    }
    if (use_wl) {
      wl_cnt  = (int*)((char*)d_ws + WL_CNT_OFF);
      wl_list = (int*)((char*)d_ws + WL_LIST_OFF);
    }
  }

  (void)hipGetLastError();

  if (wfrag) {
    pack_w<<<7, 256, 0, stream>>>(W1, W2, W3, wfrag, wl_cnt);
    if (use_wl)
      classify<<<nblk, 256, 0, stream>>>(x, Bn, wl_cnt, wl_list, nbuck, cap);
    MatrixMLP_54047868453544_kernel<<<nblk, 256, 0, stream>>>(
        x, b1, b2, b3, wfrag, out, Bn);
    const int rblk = use_wl ? (nbuck * (RBLK / NBUCK)) : RBLK;
    repair_rows<<<rblk, 256, 0, stream>>>(x, W1, b1, W2, b2, W3, b3, wfrag,
                                          out, Bn, wl_cnt, wl_list,
                                          use_wl, nbuck, cap, /*write_all=*/0);
  } else {
    // ws too small for weight fragments (never observed): full Jacobi+MFMA
    // pass over ALL rows -- slow but correct.
    repair_rows<<<RBLK, 256, 0, stream>>>(x, W1, b1, W2, b2, W3, b3, nullptr,
                                          out, Bn, nullptr, nullptr,
                                          /*use_wl=*/0, 1, 0, /*write_all=*/1);
  }

  hipError_t e = hipGetLastError();
  if (e != hipSuccess) {
    int byte = 0x40 + ((int)e & 63);
    hipMemsetAsync(d_out, byte, (size_t)out_size * sizeof(float), stream);
  }
}

// Round 14
// 61.845 us; speedup vs baseline: 13.4171x; 1.0966x over previous
//
#include <hip/hip_runtime.h>

// MatrixMLP round 14: classify folded into the (now slim) hot kernel.
//  - r13 established the scratch-spill trigger was non-SROA'd local arrays +
//    dead fallback branches, NOT the worklist append.  With the slim kernel,
//    the append (ballot + 1 bucketed atomic/wave) goes back into the hot
//    kernel, using the EXACT guard predicate it already computes.
//  - Pipeline: pack_w -> hot (solve+MLP+append) -> repair (wave-parallel
//    Jacobi+MFMA over dense bucketed worklist).  One 40MB pass and one
//    launch removed vs round 13.

typedef __attribute__((ext_vector_type(8))) short short8;
typedef __attribute__((ext_vector_type(4))) float f32x4;

__device__ __forceinline__ short f2bf(float f) {
  unsigned int u = __float_as_uint(f);
  u += 0x7fffu + ((u >> 16) & 1u);
  return (short)(u >> 16);
}
__device__ __forceinline__ float cl01(float v) {
  if (v != v) v = 0.0f;
  return fminf(fmaxf(v, 0.0f), 1.0f);
}

#define GUARD_THETA 1.0e-4f
#define WFRAG_BYTES 26624        // 26 frags * 64 lanes * 16 B
#define WL_CNT_OFF  26624        // 32 counters, stride 32 ints (128 B)
#define WL_LIST_OFF 30720
#define NBUCK 32
#define RBLK 256

// ---- per-wave LDS chunk (bytes) ----
#define W_A    0        // 64 rows * 80 B
#define W_H1   5120     // 16 rows * 272 B
#define W_H2   9472     // 16 rows * 144 B
#define W_D    11776    // 64 rows * 20 B
#define W_SZ   13056
#define SMEM_SZ (4 * W_SZ)   // 52224 B -> 3 blocks/CU

// ---------------- weight fragment pre-pack (+ counter reset) ----------------
__global__ void pack_w(const float* __restrict__ W1, const float* __restrict__ W2,
                       const float* __restrict__ W3, short* __restrict__ ws,
                       int* __restrict__ wl_cnt)
{
  if (wl_cnt && blockIdx.x == 0 && threadIdx.x < NBUCK)
    wl_cnt[threadIdx.x * 32] = 0;
  int t = blockIdx.x * 256 + threadIdx.x;
  if (t >= 26 * 64) return;
  int fid = t >> 6, lane = t & 63, l15 = lane & 15, lg = lane >> 4;
  short8 v;
  if (fid < 8) {
    int col = fid * 16 + l15;
    #pragma unroll
    for (int j = 0; j < 8; ++j) {
      int k = lg * 8 + j;
      v[j] = (k < 24) ? f2bf(W1[k * 128 + col]) : (short)0;
    }
  } else if (fid < 24) {
    int q = fid - 8, kt = q >> 2, nt = q & 3, col = nt * 16 + l15;
    #pragma unroll
    for (int j = 0; j < 8; ++j)
      v[j] = f2bf(W2[(kt * 32 + lg * 8 + j) * 64 + col]);
  } else {
    int kt = fid - 24;
    #pragma unroll
    for (int j = 0; j < 8; ++j)
      v[j] = (l15 < 4) ? f2bf(W3[(kt * 32 + lg * 8 + j) * 4 + l15]) : (short)0;
  }
  ((short8*)ws)[t] = v;
}

// ---------------- shared MFMA MLP body (barrier-synced) ----------------
template <bool WF>
__device__ __forceinline__ void mlp_wave(
    unsigned char* wsm, int lane, int l15, int lg,
    const short8* __restrict__ wv4,
    const float* __restrict__ W1, const float* __restrict__ W2,
    const float* __restrict__ W3,
    const float* __restrict__ b1, const float* __restrict__ b2,
    const float* __restrict__ b3)
{
  const f32x4 fzero = {0.0f, 0.0f, 0.0f, 0.0f};

  short8 bf1[8];
  if constexpr (WF) {
    #pragma unroll
    for (int nt = 0; nt < 8; ++nt) bf1[nt] = wv4[nt * 64 + lane];
  } else {
    #pragma unroll
    for (int nt = 0; nt < 8; ++nt) {
      int col = nt * 16 + l15;
      #pragma unroll
      for (int j = 0; j < 8; ++j) {
        int k = lg * 8 + j;
        bf1[nt][j] = (k < 24) ? f2bf(W1[k * 128 + col]) : (short)0;
      }
    }
  }
  float bias1[8], bias2[4], bias3;
  #pragma unroll
  for (int nt = 0; nt < 8; ++nt) bias1[nt] = b1[nt * 16 + l15];
  #pragma unroll
  for (int nt = 0; nt < 4; ++nt) bias2[nt] = b2[nt * 16 + l15];
  bias3 = b3[l15 & 3];

  __syncthreads();   // A-rows visible

  for (int t = 0; t < 4; ++t) {
    // layer 1: (16x32)@(32x128) + b1, ReLU -> H1 tile
    {
      short8 a = *(const short8*)(wsm + W_A + (t * 16 + l15) * 80 + lg * 16);
      f32x4 acc[8];
      #pragma unroll
      for (int nt = 0; nt < 8; ++nt)
        acc[nt] = __builtin_amdgcn_mfma_f32_16x16x32_bf16(a, bf1[nt], fzero, 0, 0, 0);
      #pragma unroll
      for (int nt = 0; nt < 8; ++nt) {
        #pragma unroll
        for (int j = 0; j < 4; ++j) {
          float h = acc[nt][j] + bias1[nt];
          h = h > 0.0f ? h : 0.0f;
          *(short*)(wsm + W_H1 + (lg * 4 + j) * 272 + (nt * 16 + l15) * 2) = f2bf(h);
        }
      }
    }
    __syncthreads();

    // layer 2: (16x128)@(128x64) + b2, ReLU -> H2 tile
    {
      f32x4 acc2[4] = {fzero, fzero, fzero, fzero};
      #pragma unroll
      for (int kt = 0; kt < 4; ++kt) {
        short8 a2 = *(const short8*)(wsm + W_H1 + l15 * 272 + kt * 64 + lg * 16);
        #pragma unroll
        for (int nt = 0; nt < 4; ++nt) {
          short8 bw;
          if constexpr (WF) {
            bw = wv4[(8 + kt * 4 + nt) * 64 + lane];
          } else {
            int col = nt * 16 + l15;
            #pragma unroll
            for (int j = 0; j < 8; ++j)
              bw[j] = f2bf(W2[(kt * 32 + lg * 8 + j) * 64 + col]);
          }
          acc2[nt] = __builtin_amdgcn_mfma_f32_16x16x32_bf16(a2, bw, acc2[nt], 0, 0, 0);
        }
      }
      #pragma unroll
      for (int nt = 0; nt < 4; ++nt) {
        #pragma unroll
        for (int j = 0; j < 4; ++j) {
          float h = acc2[nt][j] + bias2[nt];
          h = h > 0.0f ? h : 0.0f;
          *(short*)(wsm + W_H2 + (lg * 4 + j) * 144 + (nt * 16 + l15) * 2) = f2bf(h);
        }
      }
    }
    __syncthreads();

    // layer 3: (16x64)@(64x16[4]) + b3 -> delta
    {
      f32x4 acc3 = fzero;
      #pragma unroll
      for (int kt = 0; kt < 2; ++kt) {
        short8 a3 = *(const short8*)(wsm + W_H2 + l15 * 144 + kt * 64 + lg * 16);
        short8 bw;
        if constexpr (WF) {
          bw = wv4[(24 + kt) * 64 + lane];
        } else {
          #pragma unroll
          for (int j = 0; j < 8; ++j)
            bw[j] = (l15 < 4) ? f2bf(W3[(kt * 32 + lg * 8 + j) * 4 + l15]) : (short)0;
        }
        acc3 = __builtin_amdgcn_mfma_f32_16x16x32_bf16(a3, bw, acc3, 0, 0, 0);
      }
      if (l15 < 4) {
        #pragma unroll
        for (int j = 0; j < 4; ++j)
          *(float*)(wsm + W_D + (t * 16 + lg * 4 + j) * 20 + l15 * 4) = acc3[j] + bias3;
      }
    }
  }
  __syncthreads();   // delta visible
}

// ---------------- hot kernel (slim + in-kernel worklist append) -------------
__global__ __launch_bounds__(256, 2) void MatrixMLP_54047868453544_kernel(
    const float* __restrict__ x,
    const float* __restrict__ b1, const float* __restrict__ b2,
    const float* __restrict__ b3,
    const short* __restrict__ wfrag,
    int* __restrict__ wl_cnt, int* __restrict__ wl_list,
    int nbuck, int cap,
    float* __restrict__ out, int Bn)
{
  __shared__ __align__(16) unsigned char smem[SMEM_SZ];
  const int tid  = threadIdx.x;
  const int lane = tid & 63;
  const int wv   = tid >> 6;
  const int l15  = lane & 15;
  const int lg   = lane >> 4;
  unsigned char* wsm = smem + wv * W_SZ;
  const long long g = (long long)blockIdx.x * 256 + wv * 64 + lane;
  const f32x4 fzero = {0.0f, 0.0f, 0.0f, 0.0f};

  // ---- load row as named vectors ----
  f32x4 v0 = fzero, v1 = fzero, v2 = fzero, v3 = fzero, v4 = fzero;
  if (g < Bn) {
    const f32x4* xr = (const f32x4*)(x + g * 20);
    v0 = xr[0]; v1 = xr[1]; v2 = xr[2]; v3 = xr[3]; v4 = xr[4];
  }

  // ---- f32 Cramer solve with safety guard; all named scalars ----
  float a00 = v0[0], a10 = v0[1], a20 = v0[2], a30 = v0[3];
  float a01 = v1[0], a11 = v1[1], a21 = v1[2], a31 = v1[3];
  float a02 = v2[0], a12 = v2[1], a22 = v2[2], a32 = v2[3];
  float a03 = v3[0], a13 = v3[1], a23 = v3[2], a33 = v3[3];
  float y0 = v4[0], y1 = v4[1], y2 = v4[2], y3 = v4[3];

  float s0 = a00*a11 - a10*a01, s1 = a00*a12 - a10*a02, s2 = a00*a13 - a10*a03;
  float s3 = a01*a12 - a11*a02, s4 = a01*a13 - a11*a03, s5 = a02*a13 - a12*a03;
  float c0 = a20*a31 - a30*a21, c1 = a20*a32 - a30*a22, c2 = a20*a33 - a30*a23;
  float c3 = a21*a32 - a31*a22, c4 = a21*a33 - a31*a23, c5 = a22*a33 - a32*a23;
  float det = s0*c5 - s1*c4 + s2*c3 + s3*c2 - s4*c1 + s5*c0;
  float T = a00*a00 + a01*a01 + a02*a02 + a03*a03
          + a10*a10 + a11*a11 + a12*a12 + a13*a13
          + a20*a20 + a21*a21 + a22*a22 + a23*a23
          + a30*a30 + a31*a31 + a32*a32 + a33*a33;

  const bool safe = __builtin_fabsf(det) > GUARD_THETA * T * T;
  float xd0 = 0.0f, xd1 = 0.0f, xd2 = 0.0f, xd3 = 0.0f;
  if (safe) {
    float rdet = 1.0f / det;
    xd0 = rdet * ((  a11*c5 - a12*c4 + a13*c3) * y0 +
                  (-(a01*c5 - a02*c4 + a03*c3)) * y1 +
                  (  a31*s5 - a32*s4 + a33*s3) * y2 +
                  (-(a21*s5 - a22*s4 + a23*s3)) * y3);
    xd1 = rdet * ((-(a10*c5 - a12*c2 + a13*c1)) * y0 +
                  (  a00*c5 - a02*c2 + a03*c1) * y1 +
                  (-(a30*s5 - a32*s2 + a33*s1)) * y2 +
                  (  a20*s5 - a22*s2 + a23*s1) * y3);
    xd2 = rdet * ((  a10*c4 - a11*c2 + a13*c0) * y0 +
                  (-(a00*c4 - a01*c2 + a03*c0)) * y1 +
                  (  a30*s4 - a31*s2 + a33*s0) * y2 +
                  (-(a20*s4 - a21*s2 + a23*s0)) * y3);
    xd3 = rdet * ((-(a10*c3 - a11*c1 + a12*c0)) * y0 +
                  (  a00*c3 - a01*c1 + a02*c0) * y1 +
                  (-(a30*s3 - a31*s1 + a32*s0)) * y2 +
                  (  a20*s3 - a21*s1 + a22*s0) * y3);
  }
  // unsafe lanes keep xd=0: placeholder, overwritten by repair kernel

  // ---- worklist append: EXACT predicate, 1 bucketed atomic per wave ----
  if (wl_list) {
    const bool unsafe_row = (!safe) && (g < Bn);
    unsigned long long m = __ballot(unsafe_row);
    if (m) {
      const int bucket = (int)blockIdx.x % nbuck;
      int leader = (int)__builtin_ctzll(m);
      int base = 0;
      if (lane == leader)
        base = atomicAdd(&wl_cnt[bucket * 32], (int)__builtin_popcountll(m));
      base = __shfl(base, leader, 64);
      if (unsafe_row) {
        int lt = (int)__builtin_popcountll(m & ((1ull << lane) - 1ull));
        wl_list[(size_t)bucket * cap + base + lt] = (int)g;
      }
    }
  }

  const float xls0 = cl01(xd0), xls1 = cl01(xd1);
  const float xls2 = cl01(xd2), xls3 = cl01(xd3);

  // ---- A-row as named short8 vectors ----
  short8 r0 = { f2bf(v0[0]), f2bf(v0[1]), f2bf(v0[2]), f2bf(v0[3]),
                f2bf(v1[0]), f2bf(v1[1]), f2bf(v1[2]), f2bf(v1[3]) };
  short8 r1 = { f2bf(v2[0]), f2bf(v2[1]), f2bf(v2[2]), f2bf(v2[3]),
                f2bf(v3[0]), f2bf(v3[1]), f2bf(v3[2]), f2bf(v3[3]) };
  short8 r2 = { f2bf(v4[0]), f2bf(v4[1]), f2bf(v4[2]), f2bf(v4[3]),
                f2bf(xls0),  f2bf(xls1),  f2bf(xls2),  f2bf(xls3) };
  short8 r3 = { 0, 0, 0, 0, 0, 0, 0, 0 };
  {
    short8* dst = (short8*)(wsm + W_A + lane * 80);
    dst[0] = r0; dst[1] = r1; dst[2] = r2; dst[3] = r3;
  }

  // ---- MFMA MLP ----
  mlp_wave<true>(wsm, lane, l15, lg, (const short8*)wfrag,
                 nullptr, nullptr, nullptr, b1, b2, b3);

  // ---- epilogue ----
  if (g < Bn) {
    const float* dl = (const float*)(wsm + W_D + lane * 20);
    f32x4 o = { fminf(fmaxf(xls0 + dl[0], 0.0f), 1.0f),
                fminf(fmaxf(xls1 + dl[1], 0.0f), 1.0f),
                fminf(fmaxf(xls2 + dl[2], 0.0f), 1.0f),
                fminf(fmaxf(xls3 + dl[3], 0.0f), 1.0f) };
    *(f32x4*)(out + g * 4) = o;
  }
}

// ---------------- repair kernel (parallel buckets / full-scan fallback) -----
__global__ __launch_bounds__(256) void repair_rows(
    const float* __restrict__ x,
    const float* __restrict__ W1, const float* __restrict__ b1,
    const float* __restrict__ W2, const float* __restrict__ b2,
    const float* __restrict__ W3, const float* __restrict__ b3,
    const short* __restrict__ wfrag,
    float* __restrict__ out, int Bn,
    const int* __restrict__ wl_cnt, const int* __restrict__ wl_list,
    int use_wl, int nbuck, int cap, int write_all)
{
  __shared__ __align__(16) unsigned char smem[SMEM_SZ];
  const int tid  = threadIdx.x;
  const int lane = tid & 63;
  const int wv   = tid >> 6;
  const int l15  = lane & 15;
  const int lg   = lane >> 4;
  unsigned char* wsm = smem + wv * W_SZ;

  const int bucket = use_wl ? ((int)blockIdx.x % nbuck) : 0;
  const int sub    = use_wl ? ((int)blockIdx.x / nbuck) : (int)blockIdx.x;
  const int nsub   = use_wl ? ((int)gridDim.x / nbuck)  : (int)gridDim.x;
  const int cnt = use_wl ? wl_cnt[bucket * 32] : Bn;
  const int* lst = wl_list + (size_t)bucket * cap;

  for (long long blk0 = (long long)sub * 256; blk0 < cnt;
       blk0 += (long long)nsub * 256) {
    const long long idx = blk0 + tid;
    int g = -1;
    if (idx < cnt) g = use_wl ? lst[idx] : (int)idx;

    float xf[20];
    if (g >= 0) {
      const float* xr = x + (long long)g * 20;
      #pragma unroll
      for (int i = 0; i < 5; ++i) {
        f32x4 v = *(const f32x4*)(xr + i * 4);
        xf[i*4+0] = v[0]; xf[i*4+1] = v[1]; xf[i*4+2] = v[2]; xf[i*4+3] = v[3];
      }
    } else {
      #pragma unroll
      for (int i = 0; i < 20; ++i) xf[i] = 0.0f;
    }

    if (!use_wl && !write_all && g >= 0) {
      // scan fallback with hot kernel present: keep only guard-failing rows
      // (1.004x looser: superset of hot-unsafe under cross-kernel ulp diffs)
      float a00 = xf[0], a01 = xf[4], a02 = xf[8],  a03 = xf[12];
      float a10 = xf[1], a11 = xf[5], a12 = xf[9],  a13 = xf[13];
      float a20 = xf[2], a21 = xf[6], a22 = xf[10], a23 = xf[14];
      float a30 = xf[3], a31 = xf[7], a32 = xf[11], a33 = xf[15];
      float s0 = a00*a11 - a10*a01, s1 = a00*a12 - a10*a02, s2 = a00*a13 - a10*a03;
      float s3 = a01*a12 - a11*a02, s4 = a01*a13 - a11*a03, s5 = a02*a13 - a12*a03;
      float c0 = a20*a31 - a30*a21, c1 = a20*a32 - a30*a22, c2 = a20*a33 - a30*a23;
      float c3 = a21*a32 - a31*a22, c4 = a21*a33 - a31*a23, c5 = a22*a33 - a32*a23;
      float det = s0*c5 - s1*c4 + s2*c3 + s3*c2 - s4*c1 + s5*c0;
      float T = a00*a00 + a01*a01 + a02*a02 + a03*a03
              + a10*a10 + a11*a11 + a12*a12 + a13*a13
              + a20*a20 + a21*a21 + a22*a22 + a23*a23
              + a30*a30 + a31*a31 + a32*a32 + a33*a33;
      if (__builtin_fabsf(det) > GUARD_THETA * 1.004f * T * T) g = -1;
    }

    // ---- f64 Jacobi eigensolve of G = H^T H + jax rcond truncation ----
    double G[4][4], V[4][4], rhs[4];
    #pragma unroll
    for (int p = 0; p < 4; ++p) {
      #pragma unroll
      for (int q = 0; q < 4; ++q) {
        double s = 0.0;
        #pragma unroll
        for (int k = 0; k < 4; ++k)
          s += (double)xf[p * 4 + k] * (double)xf[q * 4 + k];
        G[p][q] = s;
        V[p][q] = (p == q) ? 1.0 : 0.0;
      }
      double s = 0.0;
      #pragma unroll
      for (int k = 0; k < 4; ++k) s += (double)xf[p * 4 + k] * (double)xf[16 + k];
      rhs[p] = s;
    }
    #pragma unroll 1
    for (int sweep = 0; sweep < 6; ++sweep) {
      #pragma unroll
      for (int pq = 0; pq < 6; ++pq) {
        constexpr int PP[6] = {0, 0, 0, 1, 1, 2};
        constexpr int QQ[6] = {1, 2, 3, 2, 3, 3};
        const int p = PP[pq], q = QQ[pq];
        double apq = G[p][q];
        double c, s;
        if (apq != 0.0) {
          double tau = (G[q][q] - G[p][p]) / (2.0 * apq);
          double t = (tau >= 0.0 ? 1.0 : -1.0) / (fabs(tau) + sqrt(1.0 + tau * tau));
          c = 1.0 / sqrt(1.0 + t * t);
          s = t * c;
        } else { c = 1.0; s = 0.0; }
        #pragma unroll
        for (int k = 0; k < 4; ++k) {
          double gpk = G[p][k], gqk = G[q][k];
          G[p][k] = c * gpk - s * gqk;
          G[q][k] = s * gpk + c * gqk;
        }
        #pragma unroll
        for (int k = 0; k < 4; ++k) {
          double gkp = G[k][p], gkq = G[k][q];
          G[k][p] = c * gkp - s * gkq;
          G[k][q] = s * gkp + c * gkq;
        }
        #pragma unroll
        for (int k = 0; k < 4; ++k) {
          double vkp = V[k][p], vkq = V[k][q];
          V[k][p] = c * vkp - s * vkq;
          V[k][q] = s * vkp + c * vkq;
        }
      }
    }
    double lam[4] = {G[0][0], G[1][1], G[2][2], G[3][3]};
    double lmax = fmax(fmax(lam[0], lam[1]), fmax(lam[2], lam[3]));
    lmax = fmax(lmax, 0.0);
    const double cut = 2.27373675443232e-11 * lmax;  // (4.7683716e-6)^2
    double xd0 = 0.0, xd1 = 0.0, xd2 = 0.0, xd3 = 0.0;
    #pragma unroll
    for (int k = 0; k < 4; ++k) {
      if (lam[k] > cut && lam[k] > 0.0) {
        double coef = (V[0][k] * rhs[0] + V[1][k] * rhs[1] +
                       V[2][k] * rhs[2] + V[3][k] * rhs[3]) / lam[k];
        xd0 += V[0][k] * coef;
        xd1 += V[1][k] * coef;
        xd2 += V[2][k] * coef;
        xd3 += V[3][k] * coef;
      }
    }

    float xls[4];
    {
      double xd[4] = {xd0, xd1, xd2, xd3};
      short rowbuf[32];
      #pragma unroll
      for (int i = 0; i < 20; ++i) rowbuf[i] = f2bf(xf[i]);
      #pragma unroll
      for (int i = 0; i < 4; ++i) {
        float v = (float)xd[i];
        if (v != v) v = 0.0f;
        v = fminf(fmaxf(v, 0.0f), 1.0f);
        xls[i] = v;
        rowbuf[20 + i] = f2bf(v);
      }
      #pragma unroll
      for (int i = 24; i < 32; ++i) rowbuf[i] = 0;
      short8* dst = (short8*)(wsm + W_A + lane * 80);
      #pragma unroll
      for (int i = 0; i < 4; ++i) dst[i] = *(short8*)(rowbuf + i * 8);
    }

    if (wfrag)
      mlp_wave<true>(wsm, lane, l15, lg, (const short8*)wfrag,
                     W1, W2, W3, b1, b2, b3);
    else
      mlp_wave<false>(wsm, lane, l15, lg, nullptr,
                      W1, W2, W3, b1, b2, b3);

    if (g >= 0) {
      const float* dl = (const float*)(wsm + W_D + lane * 20);
      f32x4 o = { fminf(fmaxf(xls[0] + dl[0], 0.0f), 1.0f),
                  fminf(fmaxf(xls[1] + dl[1], 0.0f), 1.0f),
                  fminf(fmaxf(xls[2] + dl[2], 0.0f), 1.0f),
                  fminf(fmaxf(xls[3] + dl[3], 0.0f), 1.0f) };
      *(f32x4*)(out + (long long)g * 4) = o;
    }
  }
}

extern "C" void kernel_launch(void* const* d_in, const int* in_sizes, int n_in,
                              void* d_out, int out_size, void* d_ws, size_t ws_size,
                              hipStream_t stream) {
  (void)n_in;
  const float* x  = (const float*)d_in[0];
  const float* W1 = (const float*)d_in[1];
  const float* b1 = (const float*)d_in[2];
  const float* W2 = (const float*)d_in[3];
  const float* b2 = (const float*)d_in[4];
  const float* W3 = (const float*)d_in[5];
  const float* b3 = (const float*)d_in[6];
  float* out = (float*)d_out;
  const int Bn = in_sizes[0] / 20;
  const int nblk = (Bn + 255) / 256;

  short* wfrag = nullptr;
  int* wl_cnt = nullptr;
  int* wl_list = nullptr;
  int use_wl = 0, nbuck = 1, cap = 0;
  if (ws_size >= (size_t)WFRAG_BYTES) wfrag = (short*)d_ws;
  {
    int cap32 = 256 * ((nblk + NBUCK - 1) / NBUCK);
    int cap1  = 256 * nblk;
    if (ws_size >= (size_t)WL_LIST_OFF + 4ull * NBUCK * (size_t)cap32) {
      nbuck = NBUCK; cap = cap32; use_wl = 1;
    } else if (ws_size >= (size_t)WL_LIST_OFF + 4ull * (size_t)cap1) {
      nbuck = 1; cap = cap1; use_wl = 1;
    }
    if (use_wl) {
      wl_cnt  = (int*)((char*)d_ws + WL_CNT_OFF);
      wl_list = (int*)((char*)d_ws + WL_LIST_OFF);
    }
  }

  (void)hipGetLastError();

  if (wfrag) {
    pack_w<<<7, 256, 0, stream>>>(W1, W2, W3, wfrag, wl_cnt);
    MatrixMLP_54047868453544_kernel<<<nblk, 256, 0, stream>>>(
        x, b1, b2, b3, wfrag,
        use_wl ? wl_cnt : nullptr, use_wl ? wl_list : nullptr,
        nbuck, cap, out, Bn);
    const int rblk = use_wl ? (nbuck * (RBLK / NBUCK)) : RBLK;
    repair_rows<<<rblk, 256, 0, stream>>>(x, W1, b1, W2, b2, W3, b3, wfrag,
                                          out, Bn, wl_cnt, wl_list,
                                          use_wl, nbuck, cap, /*write_all=*/0);
  } else {
    // ws too small for weight fragments (never observed): full Jacobi+MFMA
    // pass over ALL rows -- slow but correct.
    repair_rows<<<RBLK, 256, 0, stream>>>(x, W1, b1, W2, b2, W3, b3, nullptr,
                                          out, Bn, nullptr, nullptr,
                                          /*use_wl=*/0, 1, 0, /*write_all=*/1);
  }

  hipError_t e = hipGetLastError();
  if (e != hipSuccess) {
    int byte = 0x40 + ((int)e & 63);
    hipMemsetAsync(d_out, byte, (size_t)out_size * sizeof(float), stream);
  }
}